// Round 7
// baseline (185.129 us; speedup 1.0000x reference)
//
#include <hip/hip_runtime.h>
#include <math.h>

#define T_ 2048
#define H_ 16

typedef __attribute__((ext_vector_type(8))) short bfx8;   // 8 bf16 = 4 VGPRs
typedef __attribute__((ext_vector_type(4))) float f32x4;  // MFMA accumulator

__device__ __forceinline__ short f2bf(float f) {
  union { float f; unsigned u; } x; x.f = f;
  unsigned r = (x.u + 0x7FFFu + ((x.u >> 16) & 1u)) >> 16;  // RNE
  return (short)r;
}
__device__ __forceinline__ float bf2f(short s) {
  union { unsigned u; float f; } x;
  x.u = ((unsigned)(unsigned short)s) << 16;
  return x.f;
}

// ---------------- prep: weight cvt + RMSNorm + Cb basis + tk table + Mt/H zero
__global__ __launch_bounds__(256) void prep_kernel(
    const float* __restrict__ Wk, const float* __restrict__ Wv,
    const float* __restrict__ Wo, const float* __restrict__ angles,
    const float* __restrict__ states, const float* __restrict__ ln_w,
    short* __restrict__ Wkb, short* __restrict__ Wvb, short* __restrict__ Wob,
    short* __restrict__ xb, short* __restrict__ Cb, short* __restrict__ tkT,
    float* __restrict__ MtH) {
  const int blk = blockIdx.x;
  if (blk < 3072) {
    const int i = blk * 256 + threadIdx.x;
    const int which = i >> 18;
    const int idx = i & 262143;
    const float* s = (which == 0) ? Wk : (which == 1) ? Wv : Wo;
    short* d = (which == 0) ? Wkb : (which == 1) ? Wvb : Wob;
    const float4 v = ((const float4*)s)[idx];
    short4 r;
    r.x = f2bf(v.x); r.y = f2bf(v.y); r.z = f2bf(v.z); r.w = f2bf(v.w);
    ((short4*)d)[idx] = r;
  } else if (blk < 7168) {
    const int row = blk - 3072;
    const int tid = threadIdx.x;
    const float4 v = ((const float4*)(states + (size_t)row * 1024))[tid];
    float ss = v.x * v.x + v.y * v.y + v.z * v.z + v.w * v.w;
#pragma unroll
    for (int off = 32; off >= 1; off >>= 1) ss += __shfl_xor(ss, off);
    __shared__ float red[4];
    if ((tid & 63) == 0) red[tid >> 6] = ss;
    __syncthreads();
    const float tot = red[0] + red[1] + red[2] + red[3];
    const float scale = rsqrtf(tot * (1.0f / 1024.0f) + 1.1920928955078125e-07f);
    const float4 w = ((const float4*)ln_w)[tid];
    short4 o;
    o.x = f2bf(v.x * scale * w.x);
    o.y = f2bf(v.y * scale * w.y);
    o.z = f2bf(v.z * scale * w.z);
    o.w = f2bf(v.w * scale * w.w);
    ((short4*)(xb + (size_t)row * 1024))[tid] = o;
  } else if (blk < 7424) {
    const int gid = (blk - 7168) * 256 + threadIdx.x;  // 64K: (t,j)
    const int j = gid & 31;
    const int t = gid >> 5;
    float s, c;
    sincosf((float)t * angles[j], &s, &c);
    Cb[(size_t)t * 64 + j] = f2bf(0.125f * c);
    Cb[(size_t)t * 64 + 32 + j] = f2bf(0.125f * s);
  } else if (blk < 7456) {
    const int gid = (blk - 7424) * 256 + threadIdx.x;  // 8K: (j, l-chunk)
    const int tc = gid & 255;
    const int j = gid >> 8;
    const float th = angles[j];
    short lo[8], hi[8];
#pragma unroll
    for (int r = 0; r < 8; ++r) {
      float s, c;
      sincosf((float)(tc * 8 + r) * th, &s, &c);
      lo[r] = f2bf((c + s) * 0.125f);
      hi[r] = f2bf((c - s) * 0.125f);
    }
    short* base = tkT + (size_t)j * 2048 + tc * 8;
    *(short4*)(base) = *(short4*)&lo[0];
    *(short4*)(base + 4) = *(short4*)&lo[4];
    short* base2 = tkT + (size_t)(32 + j) * 2048 + tc * 8;
    *(short4*)(base2) = *(short4*)&hi[0];
    *(short4*)(base2 + 4) = *(short4*)&hi[4];
  } else {  // zero Mt (512 KB) + H (512 KB): 65536 float4s
    const int gid = (blk - 7456) * 256 + threadIdx.x;
    ((float4*)MtH)[gid] = make_float4(0.f, 0.f, 0.f, 0.f);
  }
}

// ------- fused K+V GEMM + masked softmax + kv + Mt accumulation -------------
// r7: NO LDS staging in the K-loop. Evidence across r2/r4/r6: every staged
// variant (dbuf, smaller tile, BK=128+XCD) sits at 43-62us with MfmaUtil ~12%,
// HBM ~6%, VALU ~15% — the global_load_lds + vmcnt(0)-drain + 2-barrier
// apparatus IS the cost, not load latency per se. Reuse math: A and B elements
// are each read by only 2 waves/block; B (2MB/matrix) is chip-L2-resident and
// A's slice L2-fits — classic "don't stage what L2 serves" (lesson #7).
// So: per kc, each wave loads 4 A-frags + 4 B-frags global->VGPR (same logical
// elements, same k-order => bit-identical sums) + 16 MFMA. No barriers in the
// loop; compiler software-pipelines the loads; 8 waves/CU free-run.
// L2 read traffic: 2x the staged version (~512MB chip-wide ~ 17 TB/s < 34.5
// ceiling). LDS keeps only Vs + kvS (33 KB) for the epilogue.
__global__ __launch_bounds__(256) void kvgemm_kernel(
    const short* __restrict__ xb, const short* __restrict__ Wkb,
    const short* __restrict__ Wvb, const float* __restrict__ bk,
    const float* __restrict__ bv, const int* __restrict__ mask,
    const short* __restrict__ tkT, float* __restrict__ Mt) {
  __shared__ short Vs[128][64];   // 16 KB
  __shared__ short kvS[64][132];  // 16.9 KB (padded: conflict-free contraction)

  const int row0 = blockIdx.x * 128;  // XCD = x%8
  const int h = blockIdx.y;
  const int t = threadIdx.x;
  const int lane = t & 63;
  const int wv = t >> 6;
  const bool isV = wv >= 2;
  const int wrow = (wv & 1) * 64;
  const int lrow = lane & 15;
  const int kgg = (lane >> 4) * 8;  // k-col group of this lane quarter

  // per-wave fragment base pointers (A rows / B rows), k advances by 32/iter
  const short* WB = isV ? Wvb : Wkb;
  const short* ab[4];
  const short* bb[4];
#pragma unroll
  for (int i = 0; i < 4; ++i)
    ab[i] = xb + (size_t)(row0 + wrow + i * 16 + lrow) * 1024 + kgg;
#pragma unroll
  for (int j = 0; j < 4; ++j)
    bb[j] = WB + (size_t)(h * 64 + j * 16 + lrow) * 1024 + kgg;

  f32x4 acc[4][4] = {};
  for (int kc = 0; kc < 32; ++kc) {  // K=32 per iter, same k-order as r3
    bfx8 af[4], bf_[4];
#pragma unroll
    for (int i = 0; i < 4; ++i) af[i] = *(const bfx8*)(ab[i] + kc * 32);
#pragma unroll
    for (int j = 0; j < 4; ++j) bf_[j] = *(const bfx8*)(bb[j] + kc * 32);
#pragma unroll
    for (int i = 0; i < 4; ++i)
#pragma unroll
      for (int j = 0; j < 4; ++j)
        acc[i][j] = __builtin_amdgcn_mfma_f32_16x16x32_bf16(af[i], bf_[j], acc[i][j], 0, 0, 0);
  }

  const int rq = (lane >> 4) * 4;
  if (isV) {  // park V+bias in Vs
#pragma unroll
    for (int j = 0; j < 4; ++j) {
      const float bb2 = bv[h * 64 + j * 16 + lrow];
#pragma unroll
      for (int i = 0; i < 4; ++i)
#pragma unroll
        for (int rr = 0; rr < 4; ++rr)
          Vs[wrow + rq + i * 16 + rr][j * 16 + lrow] = f2bf(acc[i][j][rr] + bb2);
    }
  }
  __syncthreads();
  if (!isV) {  // masked softmax over head dim, kv = softmax * V -> kvS[d][l]
    float bkc[4];
#pragma unroll
    for (int j = 0; j < 4; ++j) bkc[j] = bk[h * 64 + j * 16 + lrow];
    const int rowg0 = row0 + wrow + rq;
#pragma unroll
    for (int i = 0; i < 4; ++i) {
#pragma unroll
      for (int rr = 0; rr < 4; ++rr) {
        const float m = (float)mask[rowg0 + i * 16 + rr];
        float kf[4];
#pragma unroll
        for (int j = 0; j < 4; ++j) kf[j] = (acc[i][j][rr] + bkc[j]) * m;
        float mx = fmaxf(fmaxf(kf[0], kf[1]), fmaxf(kf[2], kf[3]));
#pragma unroll
        for (int off = 8; off >= 1; off >>= 1) mx = fmaxf(mx, __shfl_xor(mx, off));
        float s = 0.0f;
#pragma unroll
        for (int j = 0; j < 4; ++j) { kf[j] = expf(kf[j] - mx); s += kf[j]; }
#pragma unroll
        for (int off = 8; off >= 1; off >>= 1) s += __shfl_xor(s, off);
        const float inv = 1.0f / s;
#pragma unroll
        for (int j = 0; j < 4; ++j)
          acc[i][j][rr] = kf[j] * inv *
                          bf2f(Vs[wrow + rq + i * 16 + rr][j * 16 + lrow]);
      }
    }
#pragma unroll
    for (int j = 0; j < 4; ++j) {
      const int d = j * 16 + lrow;
#pragma unroll
      for (int i = 0; i < 4; ++i) {
        short4 o;
        o.x = f2bf(acc[i][j][0]); o.y = f2bf(acc[i][j][1]);
        o.z = f2bf(acc[i][j][2]); o.w = f2bf(acc[i][j][3]);
        *(short4*)&kvS[d][wrow + rq + i * 16] = o;
      }
    }
  }
  __syncthreads();
  // Mt contraction: wave w covers e in [w*16, w*16+16), K = 128 local l.
  const int bbb = row0 >> 11;
  const int tb = row0 & 2047;
  const short* tkb = tkT + (size_t)(wv * 16 + lrow) * 2048 + tb;
  const int kg = (lane >> 4) * 8;
  f32x4 macc[4] = {};
#pragma unroll
  for (int kc = 0; kc < 4; ++kc) {
    const bfx8 af = *(const bfx8*)(tkb + kc * 32 + kg);
#pragma unroll
    for (int j = 0; j < 4; ++j) {
      const bfx8 bf_ = *(const bfx8*)&kvS[j * 16 + lrow][kc * 32 + kg];
      macc[j] = __builtin_amdgcn_mfma_f32_16x16x32_bf16(af, bf_, macc[j], 0, 0, 0);
    }
  }
  float* Mb = Mt + (size_t)(bbb * 16 + h) * 4096;
#pragma unroll
  for (int j = 0; j < 4; ++j) {
    const int d = j * 16 + lrow;
#pragma unroll
    for (int rr = 0; rr < 4; ++rr) {
      const int e = wv * 16 + rq + rr;
      atomicAdd(&Mb[(size_t)e * 64 + d], macc[j][rr]);
    }
  }
}

// ---------------- fold fused into hgemm (proven r1-r3) ---------------------
// H[b][o][kap] = sum_k Wo[o][k] Mf[b][kap][k]; fold applied in-register:
//   Mf[b][a][h*64+d]    = p*Mt[b,h][a][d] + q*Mt[b,h][32+a][d]
//   Mf[b][32+a][h*64+d] = q*Mt[b,h][a][d] - p*Mt[b,h][32+a][d]
// 256 blocks: (h2:8 head pairs) x (ot:16 o-tiles) x (b:2), K=128 per block.
__global__ __launch_bounds__(256) void foldhgemm_kernel(
    const short* __restrict__ Wob, const float* __restrict__ Mt,
    const float* __restrict__ angles, const float* __restrict__ delta,
    float* __restrict__ H) {
  const int bid = blockIdx.x;
  const int t = threadIdx.x;
  const int lane = t & 63;
  const int w = t >> 6;
  const int lrow = lane & 15;
  const int kg = (lane >> 4) * 8;
  const int h2 = bid & 7;
  const int ot = (bid >> 3) & 15;
  const int b = bid >> 7;
  const int orow = ot * 64 + w * 16 + lrow;
  float p[2][2], q[2][2];
#pragma unroll
  for (int hh = 0; hh < 2; ++hh) {
    const float dl = delta[h2 * 2 + hh];
#pragma unroll
    for (int aa = 0; aa < 2; ++aa) {
      float s, c;
      sincosf(dl * angles[aa * 16 + lrow], &s, &c);
      p[hh][aa] = c + s;
      q[hh][aa] = c - s;
    }
  }
  f32x4 acc[4] = {};
#pragma unroll
  for (int ks = 0; ks < 4; ++ks) {
    const int hh = ks >> 1;
    const int h = h2 * 2 + hh;
    const int d0 = (ks & 1) * 32 + kg;
    const float* Mthb = Mt + (size_t)(b * 16 + h) * 4096;
    const bfx8 af = *(const bfx8*)(Wob + (size_t)orow * 1024 + h * 64 + d0);
    float m0a[8], m1a[8], m0b[8], m1b[8];
    *(float4*)&m0a[0] = *(const float4*)(Mthb + lrow * 64 + d0);
    *(float4*)&m0a[4] = *(const float4*)(Mthb + lrow * 64 + d0 + 4);
    *(float4*)&m1a[0] = *(const float4*)(Mthb + (32 + lrow) * 64 + d0);
    *(float4*)&m1a[4] = *(const float4*)(Mthb + (32 + lrow) * 64 + d0 + 4);
    *(float4*)&m0b[0] = *(const float4*)(Mthb + (16 + lrow) * 64 + d0);
    *(float4*)&m0b[4] = *(const float4*)(Mthb + (16 + lrow) * 64 + d0 + 4);
    *(float4*)&m1b[0] = *(const float4*)(Mthb + (48 + lrow) * 64 + d0);
    *(float4*)&m1b[4] = *(const float4*)(Mthb + (48 + lrow) * 64 + d0 + 4);
    bfx8 bf0, bf1, bf2, bf3;
#pragma unroll
    for (int e = 0; e < 8; ++e) {
      bf0[e] = f2bf(p[hh][0] * m0a[e] + q[hh][0] * m1a[e]);
      bf1[e] = f2bf(p[hh][1] * m0b[e] + q[hh][1] * m1b[e]);
      bf2[e] = f2bf(q[hh][0] * m0a[e] - p[hh][0] * m1a[e]);
      bf3[e] = f2bf(q[hh][1] * m0b[e] - p[hh][1] * m1b[e]);
    }
    acc[0] = __builtin_amdgcn_mfma_f32_16x16x32_bf16(af, bf0, acc[0], 0, 0, 0);
    acc[1] = __builtin_amdgcn_mfma_f32_16x16x32_bf16(af, bf1, acc[1], 0, 0, 0);
    acc[2] = __builtin_amdgcn_mfma_f32_16x16x32_bf16(af, bf2, acc[2], 0, 0, 0);
    acc[3] = __builtin_amdgcn_mfma_f32_16x16x32_bf16(af, bf3, acc[3], 0, 0, 0);
  }
  float* Hb = H + (size_t)b * 65536;
  const int rq = (lane >> 4) * 4;
#pragma unroll
  for (int j = 0; j < 4; ++j) {
    const int kap = j * 16 + lrow;
#pragma unroll
    for (int rr = 0; rr < 4; ++rr) {
      const int o = ot * 64 + w * 16 + rq + rr;
      atomicAdd(&Hb[(size_t)o * 64 + kap], acc[j][rr]);
    }
  }
}

// ---------------- out[b][t][o] = sum_kap Cb[t][kap]*H[b][o][kap] + bo[o] ----
__global__ __launch_bounds__(256) void ofinal_kernel(
    const short* __restrict__ Cb, const float* __restrict__ H,
    const float* __restrict__ bo, float* __restrict__ out) {
  const int col0 = blockIdx.x * 128;
  const int row0 = blockIdx.y * 128;
  const int b = blockIdx.z;
  float* C = out + (size_t)b * 2097152;
  const float* Hb = H + (size_t)b * 65536;
  const int t = threadIdx.x;
  const int lane = t & 63;
  const int wv = t >> 6;
  const int wm = (wv & 1) * 64, wn = (wv >> 1) * 64;
  const int lrow = lane & 15;
  const int kg = (lane >> 4) * 8;
  f32x4 acc[4][4] = {};
#pragma unroll
  for (int k0 = 0; k0 < 64; k0 += 32) {
    bfx8 af[4], bf_[4];
#pragma unroll
    for (int i = 0; i < 4; ++i)
      af[i] = *(const bfx8*)(Cb + (size_t)(row0 + wm + i * 16 + lrow) * 64 + k0 + kg);
#pragma unroll
    for (int j = 0; j < 4; ++j) {
      const float* hp = Hb + (size_t)(col0 + wn + j * 16 + lrow) * 64 + k0 + kg;
      const float4 h0 = *(const float4*)hp;
      const float4 h1 = *(const float4*)(hp + 4);
      bfx8 bb;
      bb[0] = f2bf(h0.x); bb[1] = f2bf(h0.y); bb[2] = f2bf(h0.z); bb[3] = f2bf(h0.w);
      bb[4] = f2bf(h1.x); bb[5] = f2bf(h1.y); bb[6] = f2bf(h1.z); bb[7] = f2bf(h1.w);
      bf_[j] = bb;
    }
#pragma unroll
    for (int i = 0; i < 4; ++i)
#pragma unroll
      for (int j = 0; j < 4; ++j)
        acc[i][j] = __builtin_amdgcn_mfma_f32_16x16x32_bf16(af[i], bf_[j], acc[i][j], 0, 0, 0);
  }
  const int rq = (lane >> 4) * 4;
#pragma unroll
  for (int j = 0; j < 4; ++j) {
    const int c = col0 + wn + j * 16 + lrow;
    const float bb = bo[c];
#pragma unroll
    for (int i = 0; i < 4; ++i) {
      const int r = row0 + wm + i * 16 + rq;
#pragma unroll
      for (int rr = 0; rr < 4; ++rr)
        C[(size_t)(r + rr) * 1024 + c] = acc[i][j][rr] + bb;
    }
  }
}

extern "C" void kernel_launch(void* const* d_in, const int* in_sizes, int n_in,
                              void* d_out, int out_size, void* d_ws, size_t ws_size,
                              hipStream_t stream) {
  (void)in_sizes; (void)n_in; (void)out_size; (void)ws_size;
  const float* states = (const float*)d_in[0];
  const int* mask = (const int*)d_in[1];
  const float* ln_w = (const float*)d_in[2];
  const float* angles = (const float*)d_in[3];
  const float* delta = (const float*)d_in[4];
  // d_in[5]=Wq, d_in[6]=q_bias provably unused (softmax row-sums are 1).
  const float* Wk = (const float*)d_in[7];
  const float* bk = (const float*)d_in[8];
  const float* Wv = (const float*)d_in[9];
  const float* bv = (const float*)d_in[10];
  const float* Wo = (const float*)d_in[11];
  const float* bo = (const float*)d_in[12];
  float* out = (float*)d_out;

  char* W = (char*)d_ws;
  short* xb  = (short*)(W);                        // 8 MB   [4096][1024]
  short* Wkb = (short*)(W + (8u << 20));           // 2 MB
  short* Wvb = (short*)(W + (10u << 20));          // 2 MB
  short* Wob = (short*)(W + (12u << 20));          // 2 MB
  short* Cb  = (short*)(W + (14u << 20));          // 256 KB [2048][64]
  short* tkT = (short*)(W + (14u << 20) + (256u << 10));  // 256 KB [64][2048]
  float* Mt  = (float*)(W + (15u << 20));          // 512 KB [32][64][64]
  float* H   = (float*)(W + (15u << 20) + (512u << 10));  // 512 KB [2][1024][64]

  prep_kernel<<<7712, 256, 0, stream>>>(Wk, Wv, Wo, angles, states, ln_w,
                                        Wkb, Wvb, Wob, xb, Cb, tkT, Mt);
  kvgemm_kernel<<<dim3(32, 16), 256, 0, stream>>>(xb, Wkb, Wvb, bk, bv, mask,
                                                  tkT, Mt);
  foldhgemm_kernel<<<256, 256, 0, stream>>>(Wob, Mt, angles, delta, H);
  ofinal_kernel<<<dim3(8, 16, 2), 256, 0, stream>>>(Cb, H, bo, out);
}

// Round 8
// 158.184 us; speedup vs baseline: 1.1703x; 1.1703x over previous
//
#include <hip/hip_runtime.h>
#include <math.h>

#define T_ 2048
#define H_ 16

typedef __attribute__((ext_vector_type(8))) short bfx8;   // 8 bf16 = 4 VGPRs
typedef __attribute__((ext_vector_type(4))) float f32x4;  // MFMA accumulator

__device__ __forceinline__ short f2bf(float f) {
  union { float f; unsigned u; } x; x.f = f;
  unsigned r = (x.u + 0x7FFFu + ((x.u >> 16) & 1u)) >> 16;  // RNE
  return (short)r;
}
__device__ __forceinline__ float bf2f(short s) {
  union { unsigned u; float f; } x;
  x.u = ((unsigned)(unsigned short)s) << 16;
  return x.f;
}

#define GLD_LDS(g, l) \
  __builtin_amdgcn_global_load_lds( \
      (const __attribute__((address_space(1))) void*)(g), \
      (__attribute__((address_space(3))) void*)(l), 16, 0, 0)

// ---------------- prep: weight cvt + RMSNorm + Cb basis + tk table ----------
// (Mt/H zeroing dropped: r8 partial buffers are fully overwritten, no atomics)
__global__ __launch_bounds__(256) void prep_kernel(
    const float* __restrict__ Wk, const float* __restrict__ Wv,
    const float* __restrict__ Wo, const float* __restrict__ angles,
    const float* __restrict__ states, const float* __restrict__ ln_w,
    short* __restrict__ Wkb, short* __restrict__ Wvb, short* __restrict__ Wob,
    short* __restrict__ xb, short* __restrict__ Cb, short* __restrict__ tkT) {
  const int blk = blockIdx.x;
  if (blk < 3072) {
    const int i = blk * 256 + threadIdx.x;
    const int which = i >> 18;
    const int idx = i & 262143;
    const float* s = (which == 0) ? Wk : (which == 1) ? Wv : Wo;
    short* d = (which == 0) ? Wkb : (which == 1) ? Wvb : Wob;
    const float4 v = ((const float4*)s)[idx];
    short4 r;
    r.x = f2bf(v.x); r.y = f2bf(v.y); r.z = f2bf(v.z); r.w = f2bf(v.w);
    ((short4*)d)[idx] = r;
  } else if (blk < 7168) {
    const int row = blk - 3072;
    const int tid = threadIdx.x;
    const float4 v = ((const float4*)(states + (size_t)row * 1024))[tid];
    float ss = v.x * v.x + v.y * v.y + v.z * v.z + v.w * v.w;
#pragma unroll
    for (int off = 32; off >= 1; off >>= 1) ss += __shfl_xor(ss, off);
    __shared__ float red[4];
    if ((tid & 63) == 0) red[tid >> 6] = ss;
    __syncthreads();
    const float tot = red[0] + red[1] + red[2] + red[3];
    const float scale = rsqrtf(tot * (1.0f / 1024.0f) + 1.1920928955078125e-07f);
    const float4 w = ((const float4*)ln_w)[tid];
    short4 o;
    o.x = f2bf(v.x * scale * w.x);
    o.y = f2bf(v.y * scale * w.y);
    o.z = f2bf(v.z * scale * w.z);
    o.w = f2bf(v.w * scale * w.w);
    ((short4*)(xb + (size_t)row * 1024))[tid] = o;
  } else if (blk < 7424) {
    const int gid = (blk - 7168) * 256 + threadIdx.x;  // 64K: (t,j)
    const int j = gid & 31;
    const int t = gid >> 5;
    float s, c;
    sincosf((float)t * angles[j], &s, &c);
    Cb[(size_t)t * 64 + j] = f2bf(0.125f * c);
    Cb[(size_t)t * 64 + 32 + j] = f2bf(0.125f * s);
  } else {
    const int gid = (blk - 7424) * 256 + threadIdx.x;  // 8K: (j, l-chunk)
    const int tc = gid & 255;
    const int j = gid >> 8;
    const float th = angles[j];
    short lo[8], hi[8];
#pragma unroll
    for (int r = 0; r < 8; ++r) {
      float s, c;
      sincosf((float)(tc * 8 + r) * th, &s, &c);
      lo[r] = f2bf((c + s) * 0.125f);
      hi[r] = f2bf((c - s) * 0.125f);
    }
    short* base = tkT + (size_t)j * 2048 + tc * 8;
    *(short4*)(base) = *(short4*)&lo[0];
    *(short4*)(base + 4) = *(short4*)&lo[4];
    short* base2 = tkT + (size_t)(32 + j) * 2048 + tc * 8;
    *(short4*)(base2) = *(short4*)&hi[0];
    *(short4*)(base2 + 4) = *(short4*)&hi[4];
  }
}

// ------- fused K+V GEMM + masked softmax + kv + Mt partial ------------------
// K-loop is r3-form EXACTLY (proven 43us local optimum; dbuf/64-row/BK128/
// no-LDS variants all regressed: 62/52/54/74us). r8 change: the 2M cross-XCD
// f32 atomicAdds into Mt (16 blocks contending per (bh)-slice) are replaced by
// plain stores into a PRIVATE partial slice Mtp[bh][rbl][64][64] — zero
// contention; foldhgemm sums the 16 slices.
__global__ __launch_bounds__(256) void kvgemm_kernel(
    const short* __restrict__ xb, const short* __restrict__ Wkb,
    const short* __restrict__ Wvb, const float* __restrict__ bk,
    const float* __restrict__ bv, const int* __restrict__ mask,
    const short* __restrict__ tkT, float* __restrict__ Mtp) {
  __shared__ short smem[16384];  // As[128][64] | Bk[64][64] | Bv[64][64] 32KB
  __shared__ short Vs[128][64];  // 16 KB
  short(*As)[64] = (short(*)[64])smem;
  short(*Bk)[64] = (short(*)[64])(smem + 8192);
  short(*Bv)[64] = (short(*)[64])(smem + 12288);
  short(*kvS)[132] = (short(*)[132])smem;  // padded overlay post-K-loop

  const int row0 = blockIdx.x * 128;  // XCD = x%8
  const int h = blockIdx.y;
  const int t = threadIdx.x;
  const int lane = t & 63;
  const int wv = t >> 6;
  const bool isV = wv >= 2;
  const int wrow = (wv & 1) * 64;
  const int lrow = lane & 15;

  const int srow8 = t >> 3;
  const int kslotS = (t & 7) ^ (srow8 & 7);
  const short* gaS = xb + (size_t)(row0 + srow8) * 1024 + kslotS * 8;
  const short* gkS = Wkb + (size_t)(h * 64 + srow8) * 1024 + kslotS * 8;
  const short* gvS = Wvb + (size_t)(h * 64 + srow8) * 1024 + kslotS * 8;
  short* laS = &As[srow8][(t & 7) * 8];
  short* lkS = &Bk[srow8][(t & 7) * 8];
  short* lvS = &Bv[srow8][(t & 7) * 8];

  f32x4 acc[4][4] = {};
  for (int k0 = 0; k0 < 1024; k0 += 64) {
    GLD_LDS(gaS + k0, laS);
    GLD_LDS(gaS + 32 * 1024 + k0, laS + 2048);
    GLD_LDS(gaS + 64 * 1024 + k0, laS + 4096);
    GLD_LDS(gaS + 96 * 1024 + k0, laS + 6144);
    GLD_LDS(gkS + k0, lkS);
    GLD_LDS(gkS + 32 * 1024 + k0, lkS + 2048);
    GLD_LDS(gvS + k0, lvS);
    GLD_LDS(gvS + 32 * 1024 + k0, lvS + 2048);
    __syncthreads();
#pragma unroll
    for (int kk = 0; kk < 2; ++kk) {
      const int pcol = ((kk * 4 + (lane >> 4)) ^ (lrow & 7)) * 8;
      bfx8 af[4], bf_[4];
#pragma unroll
      for (int i = 0; i < 4; ++i)
        af[i] = *(const bfx8*)&As[wrow + i * 16 + lrow][pcol];
      const short(*Bs)[64] = isV ? Bv : Bk;
#pragma unroll
      for (int j = 0; j < 4; ++j)
        bf_[j] = *(const bfx8*)&Bs[j * 16 + lrow][pcol];
#pragma unroll
      for (int i = 0; i < 4; ++i)
#pragma unroll
        for (int j = 0; j < 4; ++j)
          acc[i][j] = __builtin_amdgcn_mfma_f32_16x16x32_bf16(af[i], bf_[j], acc[i][j], 0, 0, 0);
    }
    __syncthreads();
  }
  const int rq = (lane >> 4) * 4;
  if (isV) {  // park V+bias in Vs
#pragma unroll
    for (int j = 0; j < 4; ++j) {
      const float bb = bv[h * 64 + j * 16 + lrow];
#pragma unroll
      for (int i = 0; i < 4; ++i)
#pragma unroll
        for (int rr = 0; rr < 4; ++rr)
          Vs[wrow + rq + i * 16 + rr][j * 16 + lrow] = f2bf(acc[i][j][rr] + bb);
    }
  }
  __syncthreads();
  if (!isV) {  // masked softmax over head dim, kv = softmax * V -> kvS[d][l]
    float bkc[4];
#pragma unroll
    for (int j = 0; j < 4; ++j) bkc[j] = bk[h * 64 + j * 16 + lrow];
    const int rowg0 = row0 + wrow + rq;
#pragma unroll
    for (int i = 0; i < 4; ++i) {
#pragma unroll
      for (int rr = 0; rr < 4; ++rr) {
        const float m = (float)mask[rowg0 + i * 16 + rr];
        float kf[4];
#pragma unroll
        for (int j = 0; j < 4; ++j) kf[j] = (acc[i][j][rr] + bkc[j]) * m;
        float mx = fmaxf(fmaxf(kf[0], kf[1]), fmaxf(kf[2], kf[3]));
#pragma unroll
        for (int off = 8; off >= 1; off >>= 1) mx = fmaxf(mx, __shfl_xor(mx, off));
        float s = 0.0f;
#pragma unroll
        for (int j = 0; j < 4; ++j) { kf[j] = expf(kf[j] - mx); s += kf[j]; }
#pragma unroll
        for (int off = 8; off >= 1; off >>= 1) s += __shfl_xor(s, off);
        const float inv = 1.0f / s;
#pragma unroll
        for (int j = 0; j < 4; ++j)
          acc[i][j][rr] = kf[j] * inv *
                          bf2f(Vs[wrow + rq + i * 16 + rr][j * 16 + lrow]);
      }
    }
#pragma unroll
    for (int j = 0; j < 4; ++j) {
      const int d = j * 16 + lrow;
#pragma unroll
      for (int i = 0; i < 4; ++i) {
        short4 o;
        o.x = f2bf(acc[i][j][0]); o.y = f2bf(acc[i][j][1]);
        o.z = f2bf(acc[i][j][2]); o.w = f2bf(acc[i][j][3]);
        *(short4*)&kvS[d][wrow + rq + i * 16] = o;
      }
    }
  }
  __syncthreads();
  // Mt contraction: wave w covers e in [w*16, w*16+16), K = 128 local l.
  const int bb = blockIdx.x >> 4;   // batch
  const int rbl = blockIdx.x & 15;  // row-block within batch -> private slice
  const int tb = row0 & 2047;
  const short* tkb = tkT + (size_t)(wv * 16 + lrow) * 2048 + tb;
  const int kg = (lane >> 4) * 8;
  f32x4 macc[4] = {};
#pragma unroll
  for (int kc = 0; kc < 4; ++kc) {
    const bfx8 af = *(const bfx8*)(tkb + kc * 32 + kg);
#pragma unroll
    for (int j = 0; j < 4; ++j) {
      const bfx8 bf_ = *(const bfx8*)&kvS[j * 16 + lrow][kc * 32 + kg];
      macc[j] = __builtin_amdgcn_mfma_f32_16x16x32_bf16(af, bf_, macc[j], 0, 0, 0);
    }
  }
  float* Mb = Mtp + (((size_t)(bb * 16 + h) * 16) + rbl) * 4096;
#pragma unroll
  for (int j = 0; j < 4; ++j) {
    const int d = j * 16 + lrow;
#pragma unroll
    for (int rr = 0; rr < 4; ++rr) {
      const int e = wv * 16 + rq + rr;
      Mb[(size_t)e * 64 + d] = macc[j][rr];  // plain store, private slice
    }
  }
}

// ---------------- fold fused into hgemm, de-atomicized ---------------------
// Block (h2, ot, b): (1) cooperatively sum the 16 Mtp slices of its 2 heads
// into LDS MtS[2][64][72] (one 512KB L2 pass, no atomics); (2) fold in-reg
// while building B-fragments; (3) plain-store into private Hp[h2][b] slice.
__global__ __launch_bounds__(256) void foldhgemm_kernel(
    const short* __restrict__ Wob, const float* __restrict__ Mtp,
    const float* __restrict__ angles, const float* __restrict__ delta,
    float* __restrict__ Hp) {
  __shared__ float MtS[2][64][72];  // 36 KB, pad 72: float4-aligned rows
  const int bid = blockIdx.x;
  const int t = threadIdx.x;
  const int lane = t & 63;
  const int w = t >> 6;
  const int lrow = lane & 15;
  const int kg = (lane >> 4) * 8;
  const int h2 = bid & 7;
  const int ot = (bid >> 3) & 15;
  const int b = bid >> 7;

  // (1) slice reduction: 2048 float4 positions over 2 heads x 64e x 16 d4
  for (int f = t; f < 2048; f += 256) {
    const int hh = f >> 10;
    const int rem = f & 1023;
    const int e = rem >> 4;
    const int d4 = (rem & 15) * 4;
    const float* src = Mtp + ((size_t)(b * 16 + h2 * 2 + hh) * 16) * 4096 +
                       (size_t)e * 64 + d4;
    float4 sum = *(const float4*)src;
#pragma unroll
    for (int rbl = 1; rbl < 16; ++rbl) {
      const float4 v = *(const float4*)(src + (size_t)rbl * 4096);
      sum.x += v.x; sum.y += v.y; sum.z += v.z; sum.w += v.w;
    }
    *(float4*)&MtS[hh][e][d4] = sum;
  }
  __syncthreads();

  const int orow = ot * 64 + w * 16 + lrow;
  float p[2][2], q[2][2];
#pragma unroll
  for (int hh = 0; hh < 2; ++hh) {
    const float dl = delta[h2 * 2 + hh];
#pragma unroll
    for (int aa = 0; aa < 2; ++aa) {
      float s, c;
      sincosf(dl * angles[aa * 16 + lrow], &s, &c);
      p[hh][aa] = c + s;
      q[hh][aa] = c - s;
    }
  }
  f32x4 acc[4] = {};
#pragma unroll
  for (int ks = 0; ks < 4; ++ks) {
    const int hh = ks >> 1;
    const int h = h2 * 2 + hh;
    const int d0 = (ks & 1) * 32 + kg;
    const bfx8 af = *(const bfx8*)(Wob + (size_t)orow * 1024 + h * 64 + d0);
    float m0a[8], m1a[8], m0b[8], m1b[8];
    *(float4*)&m0a[0] = *(const float4*)&MtS[hh][lrow][d0];
    *(float4*)&m0a[4] = *(const float4*)&MtS[hh][lrow][d0 + 4];
    *(float4*)&m1a[0] = *(const float4*)&MtS[hh][32 + lrow][d0];
    *(float4*)&m1a[4] = *(const float4*)&MtS[hh][32 + lrow][d0 + 4];
    *(float4*)&m0b[0] = *(const float4*)&MtS[hh][16 + lrow][d0];
    *(float4*)&m0b[4] = *(const float4*)&MtS[hh][16 + lrow][d0 + 4];
    *(float4*)&m1b[0] = *(const float4*)&MtS[hh][48 + lrow][d0];
    *(float4*)&m1b[4] = *(const float4*)&MtS[hh][48 + lrow][d0 + 4];
    bfx8 bf0, bf1, bf2, bf3;
#pragma unroll
    for (int e = 0; e < 8; ++e) {
      bf0[e] = f2bf(p[hh][0] * m0a[e] + q[hh][0] * m1a[e]);
      bf1[e] = f2bf(p[hh][1] * m0b[e] + q[hh][1] * m1b[e]);
      bf2[e] = f2bf(q[hh][0] * m0a[e] - p[hh][0] * m1a[e]);
      bf3[e] = f2bf(q[hh][1] * m0b[e] - p[hh][1] * m1b[e]);
    }
    acc[0] = __builtin_amdgcn_mfma_f32_16x16x32_bf16(af, bf0, acc[0], 0, 0, 0);
    acc[1] = __builtin_amdgcn_mfma_f32_16x16x32_bf16(af, bf1, acc[1], 0, 0, 0);
    acc[2] = __builtin_amdgcn_mfma_f32_16x16x32_bf16(af, bf2, acc[2], 0, 0, 0);
    acc[3] = __builtin_amdgcn_mfma_f32_16x16x32_bf16(af, bf3, acc[3], 0, 0, 0);
  }
  float* Hb = Hp + (size_t)(h2 * 2 + b) * 65536;  // private slice, plain store
  const int rq = (lane >> 4) * 4;
#pragma unroll
  for (int j = 0; j < 4; ++j) {
    const int kap = j * 16 + lrow;
#pragma unroll
    for (int rr = 0; rr < 4; ++rr) {
      const int o = ot * 64 + w * 16 + rq + rr;
      Hb[(size_t)o * 64 + kap] = acc[j][rr];
    }
  }
}

// ---------------- out[b][t][o] = sum_kap Cb[t][kap]*Hsum[o][kap] + bo[o] ----
// Sums the 8 h2-partial Hp slices while building the B-fragment.
__global__ __launch_bounds__(256) void ofinal_kernel(
    const short* __restrict__ Cb, const float* __restrict__ Hp,
    const float* __restrict__ bo, float* __restrict__ out) {
  const int col0 = blockIdx.x * 128;
  const int row0 = blockIdx.y * 128;
  const int b = blockIdx.z;
  float* C = out + (size_t)b * 2097152;
  const int t = threadIdx.x;
  const int lane = t & 63;
  const int wv = t >> 6;
  const int wm = (wv & 1) * 64, wn = (wv >> 1) * 64;
  const int lrow = lane & 15;
  const int kg = (lane >> 4) * 8;
  f32x4 acc[4][4] = {};
#pragma unroll
  for (int k0 = 0; k0 < 64; k0 += 32) {
    bfx8 af[4], bf_[4];
#pragma unroll
    for (int i = 0; i < 4; ++i)
      af[i] = *(const bfx8*)(Cb + (size_t)(row0 + wm + i * 16 + lrow) * 64 + k0 + kg);
#pragma unroll
    for (int j = 0; j < 4; ++j) {
      const size_t off = (size_t)(col0 + wn + j * 16 + lrow) * 64 + k0 + kg;
      float4 h0 = make_float4(0.f, 0.f, 0.f, 0.f);
      float4 h1 = make_float4(0.f, 0.f, 0.f, 0.f);
#pragma unroll
      for (int s = 0; s < 8; ++s) {
        const float* P = Hp + (size_t)(s * 2 + b) * 65536 + off;
        const float4 a0 = *(const float4*)P;
        const float4 a1 = *(const float4*)(P + 4);
        h0.x += a0.x; h0.y += a0.y; h0.z += a0.z; h0.w += a0.w;
        h1.x += a1.x; h1.y += a1.y; h1.z += a1.z; h1.w += a1.w;
      }
      bfx8 bb;
      bb[0] = f2bf(h0.x); bb[1] = f2bf(h0.y); bb[2] = f2bf(h0.z); bb[3] = f2bf(h0.w);
      bb[4] = f2bf(h1.x); bb[5] = f2bf(h1.y); bb[6] = f2bf(h1.z); bb[7] = f2bf(h1.w);
      bf_[j] = bb;
    }
#pragma unroll
    for (int i = 0; i < 4; ++i)
#pragma unroll
      for (int j = 0; j < 4; ++j)
        acc[i][j] = __builtin_amdgcn_mfma_f32_16x16x32_bf16(af[i], bf_[j], acc[i][j], 0, 0, 0);
  }
  const int rq = (lane >> 4) * 4;
#pragma unroll
  for (int j = 0; j < 4; ++j) {
    const int c = col0 + wn + j * 16 + lrow;
    const float bb = bo[c];
#pragma unroll
    for (int i = 0; i < 4; ++i) {
      const int r = row0 + wm + i * 16 + rq;
#pragma unroll
      for (int rr = 0; rr < 4; ++rr)
        C[(size_t)(r + rr) * 1024 + c] = acc[i][j][rr] + bb;
    }
  }
}

extern "C" void kernel_launch(void* const* d_in, const int* in_sizes, int n_in,
                              void* d_out, int out_size, void* d_ws, size_t ws_size,
                              hipStream_t stream) {
  (void)in_sizes; (void)n_in; (void)out_size; (void)ws_size;
  const float* states = (const float*)d_in[0];
  const int* mask = (const int*)d_in[1];
  const float* ln_w = (const float*)d_in[2];
  const float* angles = (const float*)d_in[3];
  const float* delta = (const float*)d_in[4];
  // d_in[5]=Wq, d_in[6]=q_bias provably unused (softmax row-sums are 1).
  const float* Wk = (const float*)d_in[7];
  const float* bk = (const float*)d_in[8];
  const float* Wv = (const float*)d_in[9];
  const float* bv = (const float*)d_in[10];
  const float* Wo = (const float*)d_in[11];
  const float* bo = (const float*)d_in[12];
  float* out = (float*)d_out;

  char* W = (char*)d_ws;
  short* xb  = (short*)(W);                        // 8 MB   [4096][1024]
  short* Wkb = (short*)(W + (8u << 20));           // 2 MB
  short* Wvb = (short*)(W + (10u << 20));          // 2 MB
  short* Wob = (short*)(W + (12u << 20));          // 2 MB
  short* Cb  = (short*)(W + (14u << 20));          // 256 KB [2048][64]
  short* tkT = (short*)(W + (14u << 20) + (256u << 10));  // 256 KB [64][2048]
  float* Mtp = (float*)(W + (15u << 20));          // 8 MB  [32 bh][16 rbl][4096]
  float* Hp  = (float*)(W + (23u << 20));          // 4 MB  [8 h2][2 b][65536]

  prep_kernel<<<7456, 256, 0, stream>>>(Wk, Wv, Wo, angles, states, ln_w,
                                        Wkb, Wvb, Wob, xb, Cb, tkT);
  kvgemm_kernel<<<dim3(32, 16), 256, 0, stream>>>(xb, Wkb, Wvb, bk, bv, mask,
                                                  tkT, Mtp);
  foldhgemm_kernel<<<256, 256, 0, stream>>>(Wob, Mtp, angles, delta, Hp);
  ofinal_kernel<<<dim3(8, 16, 2), 256, 0, stream>>>(Cb, Hp, bo, out);
}

// Round 9
// 145.023 us; speedup vs baseline: 1.2765x; 1.0908x over previous
//
#include <hip/hip_runtime.h>
#include <math.h>

#define T_ 2048
#define H_ 16

typedef __attribute__((ext_vector_type(8))) short bfx8;   // 8 bf16 = 4 VGPRs
typedef __attribute__((ext_vector_type(4))) float f32x4;  // MFMA accumulator

__device__ __forceinline__ short f2bf(float f) {
  union { float f; unsigned u; } x; x.f = f;
  unsigned r = (x.u + 0x7FFFu + ((x.u >> 16) & 1u)) >> 16;  // RNE
  return (short)r;
}
__device__ __forceinline__ float bf2f(short s) {
  union { unsigned u; float f; } x;
  x.u = ((unsigned)(unsigned short)s) << 16;
  return x.f;
}

#define GLD_LDS(g, l) \
  __builtin_amdgcn_global_load_lds( \
      (const __attribute__((address_space(1))) void*)(g), \
      (__attribute__((address_space(3))) void*)(l), 16, 0, 0)

// ---------------- prep: weight cvt + RMSNorm + Cb basis + tk table + Mt/H zero
__global__ __launch_bounds__(256) void prep_kernel(
    const float* __restrict__ Wk, const float* __restrict__ Wv,
    const float* __restrict__ Wo, const float* __restrict__ angles,
    const float* __restrict__ states, const float* __restrict__ ln_w,
    short* __restrict__ Wkb, short* __restrict__ Wvb, short* __restrict__ Wob,
    short* __restrict__ xb, short* __restrict__ Cb, short* __restrict__ tkT,
    float* __restrict__ MtH) {
  const int blk = blockIdx.x;
  if (blk < 3072) {
    const int i = blk * 256 + threadIdx.x;
    const int which = i >> 18;
    const int idx = i & 262143;
    const float* s = (which == 0) ? Wk : (which == 1) ? Wv : Wo;
    short* d = (which == 0) ? Wkb : (which == 1) ? Wvb : Wob;
    const float4 v = ((const float4*)s)[idx];
    short4 r;
    r.x = f2bf(v.x); r.y = f2bf(v.y); r.z = f2bf(v.z); r.w = f2bf(v.w);
    ((short4*)d)[idx] = r;
  } else if (blk < 7168) {
    const int row = blk - 3072;
    const int tid = threadIdx.x;
    const float4 v = ((const float4*)(states + (size_t)row * 1024))[tid];
    float ss = v.x * v.x + v.y * v.y + v.z * v.z + v.w * v.w;
#pragma unroll
    for (int off = 32; off >= 1; off >>= 1) ss += __shfl_xor(ss, off);
    __shared__ float red[4];
    if ((tid & 63) == 0) red[tid >> 6] = ss;
    __syncthreads();
    const float tot = red[0] + red[1] + red[2] + red[3];
    const float scale = rsqrtf(tot * (1.0f / 1024.0f) + 1.1920928955078125e-07f);
    const float4 w = ((const float4*)ln_w)[tid];
    short4 o;
    o.x = f2bf(v.x * scale * w.x);
    o.y = f2bf(v.y * scale * w.y);
    o.z = f2bf(v.z * scale * w.z);
    o.w = f2bf(v.w * scale * w.w);
    ((short4*)(xb + (size_t)row * 1024))[tid] = o;
  } else if (blk < 7424) {
    const int gid = (blk - 7168) * 256 + threadIdx.x;  // 64K: (t,j)
    const int j = gid & 31;
    const int t = gid >> 5;
    float s, c;
    sincosf((float)t * angles[j], &s, &c);
    Cb[(size_t)t * 64 + j] = f2bf(0.125f * c);
    Cb[(size_t)t * 64 + 32 + j] = f2bf(0.125f * s);
  } else if (blk < 7456) {
    const int gid = (blk - 7424) * 256 + threadIdx.x;  // 8K: (j, l-chunk)
    const int tc = gid & 255;
    const int j = gid >> 8;
    const float th = angles[j];
    short lo[8], hi[8];
#pragma unroll
    for (int r = 0; r < 8; ++r) {
      float s, c;
      sincosf((float)(tc * 8 + r) * th, &s, &c);
      lo[r] = f2bf((c + s) * 0.125f);
      hi[r] = f2bf((c - s) * 0.125f);
    }
    short* base = tkT + (size_t)j * 2048 + tc * 8;
    *(short4*)(base) = *(short4*)&lo[0];
    *(short4*)(base + 4) = *(short4*)&lo[4];
    short* base2 = tkT + (size_t)(32 + j) * 2048 + tc * 8;
    *(short4*)(base2) = *(short4*)&hi[0];
    *(short4*)(base2 + 4) = *(short4*)&hi[4];
  } else {  // zero Mt (512 KB) + H (512 KB): 65536 float4s
    const int gid = (blk - 7456) * 256 + threadIdx.x;
    ((float4*)MtH)[gid] = make_float4(0.f, 0.f, 0.f, 0.f);
  }
}

// ------- fused K+V GEMM + masked softmax + kv + Mt accumulation -------------
// r9: r3 structure and traffic EXACTLY (tile 128, BK=64, XOR-8 swizzle, atomic
// Mt — r8 proved partials+reread are worse), but 512 THREADS/BLOCK (8 waves):
// same grid dim3(32,16), same LDS 48KB (3 blocks/CU), same bytes staged, same
// k-order per output element — only change is 2x resident waves per CU
// (12 -> 24) to cover the 16 per-step vmcnt(0) drains. This isolates TLP from
// traffic (r4 confounded them). Ablation history: dbuf 62us, 64-row 52us,
// BK128+XCD 54us, no-LDS 74us, de-atomic 55us, r3 form 43us.
__global__ __launch_bounds__(512, 4) void kvgemm_kernel(
    const short* __restrict__ xb, const short* __restrict__ Wkb,
    const short* __restrict__ Wvb, const float* __restrict__ bk,
    const float* __restrict__ bv, const int* __restrict__ mask,
    const short* __restrict__ tkT, float* __restrict__ Mt) {
  __shared__ short smem[16384];  // As[128][64] | Bk[64][64] | Bv[64][64] 32KB
  __shared__ short Vs[128][64];  // 16 KB
  short(*As)[64] = (short(*)[64])smem;
  short(*Bk)[64] = (short(*)[64])(smem + 8192);
  short(*Bv)[64] = (short(*)[64])(smem + 12288);
  short(*kvS)[132] = (short(*)[132])smem;  // padded overlay post-K-loop

  const int row0 = blockIdx.x * 128;  // XCD = x%8
  const int h = blockIdx.y;
  const int t = threadIdx.x;          // 0..511
  const int lane = t & 63;
  const int wv = t >> 6;              // 0..7
  const bool isV = wv >= 4;
  const int wrow = (wv & 3) * 32;     // 32-row band per wave
  const int lrow = lane & 15;

  // staging: thread t owns physical slot t&7 of row t>>3 (0..63); fetches
  // k-slot (t&7)^(row&7). Two A issues (+0, +64 rows), one each for Bk/Bv.
  const int srow8 = t >> 3;  // 0..63
  const int kslotS = (t & 7) ^ (srow8 & 7);
  const short* gaS = xb + (size_t)(row0 + srow8) * 1024 + kslotS * 8;
  const short* gkS = Wkb + (size_t)(h * 64 + srow8) * 1024 + kslotS * 8;
  const short* gvS = Wvb + (size_t)(h * 64 + srow8) * 1024 + kslotS * 8;
  short* laS = &As[srow8][(t & 7) * 8];
  short* lkS = &Bk[srow8][(t & 7) * 8];
  short* lvS = &Bv[srow8][(t & 7) * 8];

  f32x4 acc[2][4] = {};
  for (int k0 = 0; k0 < 1024; k0 += 64) {
    GLD_LDS(gaS + k0, laS);
    GLD_LDS(gaS + 64 * 1024 + k0, laS + 4096);
    GLD_LDS(gkS + k0, lkS);
    GLD_LDS(gvS + k0, lvS);
    __syncthreads();
#pragma unroll
    for (int kk = 0; kk < 2; ++kk) {
      const int pcol = ((kk * 4 + (lane >> 4)) ^ (lrow & 7)) * 8;
      bfx8 af[2], bf_[4];
#pragma unroll
      for (int i = 0; i < 2; ++i)
        af[i] = *(const bfx8*)&As[wrow + i * 16 + lrow][pcol];
      const short(*Bs)[64] = isV ? Bv : Bk;
#pragma unroll
      for (int j = 0; j < 4; ++j)
        bf_[j] = *(const bfx8*)&Bs[j * 16 + lrow][pcol];
#pragma unroll
      for (int i = 0; i < 2; ++i)
#pragma unroll
        for (int j = 0; j < 4; ++j)
          acc[i][j] = __builtin_amdgcn_mfma_f32_16x16x32_bf16(af[i], bf_[j], acc[i][j], 0, 0, 0);
    }
    __syncthreads();
  }
  const int rq = (lane >> 4) * 4;
  if (isV) {  // park V+bias in Vs; V-waves cover rows wrow..wrow+31
#pragma unroll
    for (int j = 0; j < 4; ++j) {
      const float bb = bv[h * 64 + j * 16 + lrow];
#pragma unroll
      for (int i = 0; i < 2; ++i)
#pragma unroll
        for (int rr = 0; rr < 4; ++rr)
          Vs[wrow + rq + i * 16 + rr][j * 16 + lrow] = f2bf(acc[i][j][rr] + bb);
    }
  }
  __syncthreads();
  if (!isV) {  // masked softmax over head dim, kv = softmax * V -> kvS[d][l]
    float bkc[4];
#pragma unroll
    for (int j = 0; j < 4; ++j) bkc[j] = bk[h * 64 + j * 16 + lrow];
    const int rowg0 = row0 + wrow + rq;
#pragma unroll
    for (int i = 0; i < 2; ++i) {
#pragma unroll
      for (int rr = 0; rr < 4; ++rr) {
        const float m = (float)mask[rowg0 + i * 16 + rr];
        float kf[4];
#pragma unroll
        for (int j = 0; j < 4; ++j) kf[j] = (acc[i][j][rr] + bkc[j]) * m;
        float mx = fmaxf(fmaxf(kf[0], kf[1]), fmaxf(kf[2], kf[3]));
#pragma unroll
        for (int off = 8; off >= 1; off >>= 1) mx = fmaxf(mx, __shfl_xor(mx, off));
        float s = 0.0f;
#pragma unroll
        for (int j = 0; j < 4; ++j) { kf[j] = expf(kf[j] - mx); s += kf[j]; }
#pragma unroll
        for (int off = 8; off >= 1; off >>= 1) s += __shfl_xor(s, off);
        const float inv = 1.0f / s;
#pragma unroll
        for (int j = 0; j < 4; ++j)
          acc[i][j][rr] = kf[j] * inv *
                          bf2f(Vs[wrow + rq + i * 16 + rr][j * 16 + lrow]);
      }
    }
#pragma unroll
    for (int j = 0; j < 4; ++j) {
      const int d = j * 16 + lrow;
#pragma unroll
      for (int i = 0; i < 2; ++i) {
        short4 o;
        o.x = f2bf(acc[i][j][0]); o.y = f2bf(acc[i][j][1]);
        o.z = f2bf(acc[i][j][2]); o.w = f2bf(acc[i][j][3]);
        *(short4*)&kvS[d][wrow + rq + i * 16] = o;
      }
    }
  }
  __syncthreads();
  // Mt contraction: waves 0-3 cover e in [wv*16, wv*16+16), K = 128 local l.
  if (wv < 4) {
    const int bb = row0 >> 11;
    const int tb = row0 & 2047;
    const short* tkb = tkT + (size_t)(wv * 16 + lrow) * 2048 + tb;
    const int kg = (lane >> 4) * 8;
    f32x4 macc[4] = {};
#pragma unroll
    for (int kc = 0; kc < 4; ++kc) {
      const bfx8 af = *(const bfx8*)(tkb + kc * 32 + kg);
#pragma unroll
      for (int j = 0; j < 4; ++j) {
        const bfx8 bf_ = *(const bfx8*)&kvS[j * 16 + lrow][kc * 32 + kg];
        macc[j] = __builtin_amdgcn_mfma_f32_16x16x32_bf16(af, bf_, macc[j], 0, 0, 0);
      }
    }
    float* Mb = Mt + (size_t)(bb * 16 + h) * 4096;
#pragma unroll
    for (int j = 0; j < 4; ++j) {
      const int d = j * 16 + lrow;
#pragma unroll
      for (int rr = 0; rr < 4; ++rr) {
        const int e = wv * 16 + rq + rr;
        atomicAdd(&Mb[(size_t)e * 64 + d], macc[j][rr]);
      }
    }
  }
}

// ---------------- fold fused into hgemm (proven r1-r3) ---------------------
// H[b][o][kap] = sum_k Wo[o][k] Mf[b][kap][k]; fold applied in-register:
//   Mf[b][a][h*64+d]    = p*Mt[b,h][a][d] + q*Mt[b,h][32+a][d]
//   Mf[b][32+a][h*64+d] = q*Mt[b,h][a][d] - p*Mt[b,h][32+a][d]
// 256 blocks: (h2:8 head pairs) x (ot:16 o-tiles) x (b:2), K=128 per block.
__global__ __launch_bounds__(256) void foldhgemm_kernel(
    const short* __restrict__ Wob, const float* __restrict__ Mt,
    const float* __restrict__ angles, const float* __restrict__ delta,
    float* __restrict__ H) {
  const int bid = blockIdx.x;
  const int t = threadIdx.x;
  const int lane = t & 63;
  const int w = t >> 6;
  const int lrow = lane & 15;
  const int kg = (lane >> 4) * 8;
  const int h2 = bid & 7;
  const int ot = (bid >> 3) & 15;
  const int b = bid >> 7;
  const int orow = ot * 64 + w * 16 + lrow;
  float p[2][2], q[2][2];
#pragma unroll
  for (int hh = 0; hh < 2; ++hh) {
    const float dl = delta[h2 * 2 + hh];
#pragma unroll
    for (int aa = 0; aa < 2; ++aa) {
      float s, c;
      sincosf(dl * angles[aa * 16 + lrow], &s, &c);
      p[hh][aa] = c + s;
      q[hh][aa] = c - s;
    }
  }
  f32x4 acc[4] = {};
#pragma unroll
  for (int ks = 0; ks < 4; ++ks) {
    const int hh = ks >> 1;
    const int h = h2 * 2 + hh;
    const int d0 = (ks & 1) * 32 + kg;
    const float* Mthb = Mt + (size_t)(b * 16 + h) * 4096;
    const bfx8 af = *(const bfx8*)(Wob + (size_t)orow * 1024 + h * 64 + d0);
    float m0a[8], m1a[8], m0b[8], m1b[8];
    *(float4*)&m0a[0] = *(const float4*)(Mthb + lrow * 64 + d0);
    *(float4*)&m0a[4] = *(const float4*)(Mthb + lrow * 64 + d0 + 4);
    *(float4*)&m1a[0] = *(const float4*)(Mthb + (32 + lrow) * 64 + d0);
    *(float4*)&m1a[4] = *(const float4*)(Mthb + (32 + lrow) * 64 + d0 + 4);
    *(float4*)&m0b[0] = *(const float4*)(Mthb + (16 + lrow) * 64 + d0);
    *(float4*)&m0b[4] = *(const float4*)(Mthb + (16 + lrow) * 64 + d0 + 4);
    *(float4*)&m1b[0] = *(const float4*)(Mthb + (48 + lrow) * 64 + d0);
    *(float4*)&m1b[4] = *(const float4*)(Mthb + (48 + lrow) * 64 + d0 + 4);
    bfx8 bf0, bf1, bf2, bf3;
#pragma unroll
    for (int e = 0; e < 8; ++e) {
      bf0[e] = f2bf(p[hh][0] * m0a[e] + q[hh][0] * m1a[e]);
      bf1[e] = f2bf(p[hh][1] * m0b[e] + q[hh][1] * m1b[e]);
      bf2[e] = f2bf(q[hh][0] * m0a[e] - p[hh][0] * m1a[e]);
      bf3[e] = f2bf(q[hh][1] * m0b[e] - p[hh][1] * m1b[e]);
    }
    acc[0] = __builtin_amdgcn_mfma_f32_16x16x32_bf16(af, bf0, acc[0], 0, 0, 0);
    acc[1] = __builtin_amdgcn_mfma_f32_16x16x32_bf16(af, bf1, acc[1], 0, 0, 0);
    acc[2] = __builtin_amdgcn_mfma_f32_16x16x32_bf16(af, bf2, acc[2], 0, 0, 0);
    acc[3] = __builtin_amdgcn_mfma_f32_16x16x32_bf16(af, bf3, acc[3], 0, 0, 0);
  }
  float* Hb = H + (size_t)b * 65536;
  const int rq = (lane >> 4) * 4;
#pragma unroll
  for (int j = 0; j < 4; ++j) {
    const int kap = j * 16 + lrow;
#pragma unroll
    for (int rr = 0; rr < 4; ++rr) {
      const int o = ot * 64 + w * 16 + rq + rr;
      atomicAdd(&Hb[(size_t)o * 64 + kap], acc[j][rr]);
    }
  }
}

// ---------------- out[b][t][o] = sum_kap Cb[t][kap]*H[b][o][kap] + bo[o] ----
__global__ __launch_bounds__(256) void ofinal_kernel(
    const short* __restrict__ Cb, const float* __restrict__ H,
    const float* __restrict__ bo, float* __restrict__ out) {
  const int col0 = blockIdx.x * 128;
  const int row0 = blockIdx.y * 128;
  const int b = blockIdx.z;
  float* C = out + (size_t)b * 2097152;
  const float* Hb = H + (size_t)b * 65536;
  const int t = threadIdx.x;
  const int lane = t & 63;
  const int wv = t >> 6;
  const int wm = (wv & 1) * 64, wn = (wv >> 1) * 64;
  const int lrow = lane & 15;
  const int kg = (lane >> 4) * 8;
  f32x4 acc[4][4] = {};
#pragma unroll
  for (int k0 = 0; k0 < 64; k0 += 32) {
    bfx8 af[4], bf_[4];
#pragma unroll
    for (int i = 0; i < 4; ++i)
      af[i] = *(const bfx8*)(Cb + (size_t)(row0 + wm + i * 16 + lrow) * 64 + k0 + kg);
#pragma unroll
    for (int j = 0; j < 4; ++j) {
      const float* hp = Hb + (size_t)(col0 + wn + j * 16 + lrow) * 64 + k0 + kg;
      const float4 h0 = *(const float4*)hp;
      const float4 h1 = *(const float4*)(hp + 4);
      bfx8 bb;
      bb[0] = f2bf(h0.x); bb[1] = f2bf(h0.y); bb[2] = f2bf(h0.z); bb[3] = f2bf(h0.w);
      bb[4] = f2bf(h1.x); bb[5] = f2bf(h1.y); bb[6] = f2bf(h1.z); bb[7] = f2bf(h1.w);
      bf_[j] = bb;
    }
#pragma unroll
    for (int i = 0; i < 4; ++i)
#pragma unroll
      for (int j = 0; j < 4; ++j)
        acc[i][j] = __builtin_amdgcn_mfma_f32_16x16x32_bf16(af[i], bf_[j], acc[i][j], 0, 0, 0);
  }
  const int rq = (lane >> 4) * 4;
#pragma unroll
  for (int j = 0; j < 4; ++j) {
    const int c = col0 + wn + j * 16 + lrow;
    const float bb = bo[c];
#pragma unroll
    for (int i = 0; i < 4; ++i) {
      const int r = row0 + wm + i * 16 + rq;
#pragma unroll
      for (int rr = 0; rr < 4; ++rr)
        C[(size_t)(r + rr) * 1024 + c] = acc[i][j][rr] + bb;
    }
  }
}

extern "C" void kernel_launch(void* const* d_in, const int* in_sizes, int n_in,
                              void* d_out, int out_size, void* d_ws, size_t ws_size,
                              hipStream_t stream) {
  (void)in_sizes; (void)n_in; (void)out_size; (void)ws_size;
  const float* states = (const float*)d_in[0];
  const int* mask = (const int*)d_in[1];
  const float* ln_w = (const float*)d_in[2];
  const float* angles = (const float*)d_in[3];
  const float* delta = (const float*)d_in[4];
  // d_in[5]=Wq, d_in[6]=q_bias provably unused (softmax row-sums are 1).
  const float* Wk = (const float*)d_in[7];
  const float* bk = (const float*)d_in[8];
  const float* Wv = (const float*)d_in[9];
  const float* bv = (const float*)d_in[10];
  const float* Wo = (const float*)d_in[11];
  const float* bo = (const float*)d_in[12];
  float* out = (float*)d_out;

  char* W = (char*)d_ws;
  short* xb  = (short*)(W);                        // 8 MB   [4096][1024]
  short* Wkb = (short*)(W + (8u << 20));           // 2 MB
  short* Wvb = (short*)(W + (10u << 20));          // 2 MB
  short* Wob = (short*)(W + (12u << 20));          // 2 MB
  short* Cb  = (short*)(W + (14u << 20));          // 256 KB [2048][64]
  short* tkT = (short*)(W + (14u << 20) + (256u << 10));  // 256 KB [64][2048]
  float* Mt  = (float*)(W + (15u << 20));          // 512 KB [32][64][64]
  float* H   = (float*)(W + (15u << 20) + (512u << 10));  // 512 KB [2][1024][64]

  prep_kernel<<<7712, 256, 0, stream>>>(Wk, Wv, Wo, angles, states, ln_w,
                                        Wkb, Wvb, Wob, xb, Cb, tkT, Mt);
  kvgemm_kernel<<<dim3(32, 16), 512, 0, stream>>>(xb, Wkb, Wvb, bk, bv, mask,
                                                  tkT, Mt);
  foldhgemm_kernel<<<256, 256, 0, stream>>>(Wob, Mt, angles, delta, H);
  ofinal_kernel<<<dim3(8, 16, 2), 256, 0, stream>>>(Cb, H, bo, out);
}

// Round 10
// 143.749 us; speedup vs baseline: 1.2879x; 1.0089x over previous
//
#include <hip/hip_runtime.h>
#include <math.h>

#define T_ 2048
#define H_ 16

typedef __attribute__((ext_vector_type(8))) short bfx8;   // 8 bf16 = 4 VGPRs
typedef __attribute__((ext_vector_type(4))) float f32x4;  // MFMA accumulator

__device__ __forceinline__ short f2bf(float f) {
  union { float f; unsigned u; } x; x.f = f;
  unsigned r = (x.u + 0x7FFFu + ((x.u >> 16) & 1u)) >> 16;  // RNE
  return (short)r;
}
__device__ __forceinline__ float bf2f(short s) {
  union { unsigned u; float f; } x;
  x.u = ((unsigned)(unsigned short)s) << 16;
  return x.f;
}

#define GLD_LDS(g, l) \
  __builtin_amdgcn_global_load_lds( \
      (const __attribute__((address_space(1))) void*)(g), \
      (__attribute__((address_space(3))) void*)(l), 16, 0, 0)

// ---------------- prep: weight cvt + RMSNorm + Cb basis + tk table + Mt/H zero
__global__ __launch_bounds__(256) void prep_kernel(
    const float* __restrict__ Wk, const float* __restrict__ Wv,
    const float* __restrict__ Wo, const float* __restrict__ angles,
    const float* __restrict__ states, const float* __restrict__ ln_w,
    short* __restrict__ Wkb, short* __restrict__ Wvb, short* __restrict__ Wob,
    short* __restrict__ xb, short* __restrict__ Cb, short* __restrict__ tkT,
    float* __restrict__ MtH) {
  const int blk = blockIdx.x;
  if (blk < 3072) {
    const int i = blk * 256 + threadIdx.x;
    const int which = i >> 18;
    const int idx = i & 262143;
    const float* s = (which == 0) ? Wk : (which == 1) ? Wv : Wo;
    short* d = (which == 0) ? Wkb : (which == 1) ? Wvb : Wob;
    const float4 v = ((const float4*)s)[idx];
    short4 r;
    r.x = f2bf(v.x); r.y = f2bf(v.y); r.z = f2bf(v.z); r.w = f2bf(v.w);
    ((short4*)d)[idx] = r;
  } else if (blk < 7168) {
    const int row = blk - 3072;
    const int tid = threadIdx.x;
    const float4 v = ((const float4*)(states + (size_t)row * 1024))[tid];
    float ss = v.x * v.x + v.y * v.y + v.z * v.z + v.w * v.w;
#pragma unroll
    for (int off = 32; off >= 1; off >>= 1) ss += __shfl_xor(ss, off);
    __shared__ float red[4];
    if ((tid & 63) == 0) red[tid >> 6] = ss;
    __syncthreads();
    const float tot = red[0] + red[1] + red[2] + red[3];
    const float scale = rsqrtf(tot * (1.0f / 1024.0f) + 1.1920928955078125e-07f);
    const float4 w = ((const float4*)ln_w)[tid];
    short4 o;
    o.x = f2bf(v.x * scale * w.x);
    o.y = f2bf(v.y * scale * w.y);
    o.z = f2bf(v.z * scale * w.z);
    o.w = f2bf(v.w * scale * w.w);
    ((short4*)(xb + (size_t)row * 1024))[tid] = o;
  } else if (blk < 7424) {
    const int gid = (blk - 7168) * 256 + threadIdx.x;  // 64K: (t,j)
    const int j = gid & 31;
    const int t = gid >> 5;
    float s, c;
    sincosf((float)t * angles[j], &s, &c);
    Cb[(size_t)t * 64 + j] = f2bf(0.125f * c);
    Cb[(size_t)t * 64 + 32 + j] = f2bf(0.125f * s);
  } else if (blk < 7456) {
    const int gid = (blk - 7424) * 256 + threadIdx.x;  // 8K: (j, l-chunk)
    const int tc = gid & 255;
    const int j = gid >> 8;
    const float th = angles[j];
    short lo[8], hi[8];
#pragma unroll
    for (int r = 0; r < 8; ++r) {
      float s, c;
      sincosf((float)(tc * 8 + r) * th, &s, &c);
      lo[r] = f2bf((c + s) * 0.125f);
      hi[r] = f2bf((c - s) * 0.125f);
    }
    short* base = tkT + (size_t)j * 2048 + tc * 8;
    *(short4*)(base) = *(short4*)&lo[0];
    *(short4*)(base + 4) = *(short4*)&lo[4];
    short* base2 = tkT + (size_t)(32 + j) * 2048 + tc * 8;
    *(short4*)(base2) = *(short4*)&hi[0];
    *(short4*)(base2 + 4) = *(short4*)&hi[4];
  } else {  // zero Mt (512 KB) + H (512 KB): 65536 float4s
    const int gid = (blk - 7456) * 256 + threadIdx.x;
    ((float4*)MtH)[gid] = make_float4(0.f, 0.f, 0.f, 0.f);
  }
}

// ------- fused K+V GEMM + masked softmax + kv + Mt accumulation -------------
// r10: extend the ONLY proven kvgemm lever (r9: 256->512 threads, 43->~39us)
// to 1024 threads (16 waves). Same grid (32,16), same tiles/traffic/k-order.
// Enablers: (a) LDS overlay — Vs and kvS are live only post-K-loop, so they
// alias the staging buffer; LDS 48 -> 32.5KB; (b) __launch_bounds__(1024,8)
// forces VGPR<=64 so 2 blocks/CU fit => 32 waves/CU (hardware max, vs r9 <=24).
// Per-wave K-loop live set shrinks to acc[1][4]+af[1]+bf[4]=36 data VGPRs
// (16-row band per wave); staging is exactly 1 A-issue + 1 B-issue per thread
// (Bk/Bv split == wave split, wave-uniform). Ablation history: dbuf 62us,
// 64-row 52us, BK128+XCD 54us, no-LDS 74us, de-atomic 55us, 256thr 43us,
// 512thr ~39us.
__global__ __launch_bounds__(1024, 8) void kvgemm_kernel(
    const short* __restrict__ xb, const short* __restrict__ Wkb,
    const short* __restrict__ Wvb, const float* __restrict__ bk,
    const float* __restrict__ bv, const int* __restrict__ mask,
    const short* __restrict__ tkT, float* __restrict__ Mt) {
  // staging: As[128][64] @0 (16KB) | Bk[64][64] @16KB | Bv[64][64] @24KB
  // post-loop overlay: Vs[128][64] @0 (16KB) | kvS[64][132] @16KB (16.9KB)
  __shared__ short smem[16640];  // 32.5 KB
  short(*As)[64] = (short(*)[64])smem;
  short(*Bk)[64] = (short(*)[64])(smem + 8192);
  short(*Bv)[64] = (short(*)[64])(smem + 12288);
  short(*Vs)[64] = (short(*)[64])smem;             // alias As (post-loop)
  short(*kvS)[132] = (short(*)[132])(smem + 8192); // alias Bk/Bv (post-softmax)

  const int row0 = blockIdx.x * 128;  // XCD = x%8
  const int h = blockIdx.y;
  const int t = threadIdx.x;          // 0..1023
  const int lane = t & 63;
  const int wv = t >> 6;              // 0..15
  const bool isV = wv >= 8;
  const int wrow = (wv & 7) * 16;     // 16-row band per wave
  const int lrow = lane & 15;

  // staging: thread t owns physical slot t&7 of row t>>3 (0..127); fetches
  // k-slot (t&7)^(row&7). One A issue each; waves 0-7 issue Bk, 8-15 Bv
  // (t<512 <=> srow8<64 <=> !isV — wave-uniform).
  const int srow8 = t >> 3;  // 0..127
  const int kslotS = (t & 7) ^ (srow8 & 7);
  const short* gaS = xb + (size_t)(row0 + srow8) * 1024 + kslotS * 8;
  const short* gbS = isV ? Wvb + (size_t)(h * 64 + srow8 - 64) * 1024 + kslotS * 8
                         : Wkb + (size_t)(h * 64 + srow8) * 1024 + kslotS * 8;
  short* laS = &As[srow8][(t & 7) * 8];
  short* lbS = isV ? &Bv[srow8 - 64][(t & 7) * 8] : &Bk[srow8][(t & 7) * 8];

  f32x4 acc[4] = {};
  for (int k0 = 0; k0 < 1024; k0 += 64) {
    GLD_LDS(gaS + k0, laS);
    GLD_LDS(gbS + k0, lbS);
    __syncthreads();
#pragma unroll
    for (int kk = 0; kk < 2; ++kk) {
      const int pcol = ((kk * 4 + (lane >> 4)) ^ (lrow & 7)) * 8;
      const bfx8 af = *(const bfx8*)&As[wrow + lrow][pcol];
      const short(*Bs)[64] = isV ? Bv : Bk;
      bfx8 bf_[4];
#pragma unroll
      for (int j = 0; j < 4; ++j)
        bf_[j] = *(const bfx8*)&Bs[j * 16 + lrow][pcol];
#pragma unroll
      for (int j = 0; j < 4; ++j)
        acc[j] = __builtin_amdgcn_mfma_f32_16x16x32_bf16(af, bf_[j], acc[j], 0, 0, 0);
    }
    __syncthreads();
  }
  const int rq = (lane >> 4) * 4;
  if (isV) {  // park V+bias in Vs (aliases As; post-K-loop, barrier-protected)
#pragma unroll
    for (int j = 0; j < 4; ++j) {
      const float bb = bv[h * 64 + j * 16 + lrow];
#pragma unroll
      for (int rr = 0; rr < 4; ++rr)
        Vs[wrow + rq + rr][j * 16 + lrow] = f2bf(acc[j][rr] + bb);
    }
  }
  __syncthreads();
  if (!isV) {  // masked softmax over head dim, kv = softmax * V -> kvS[d][l]
    float bkc[4];
#pragma unroll
    for (int j = 0; j < 4; ++j) bkc[j] = bk[h * 64 + j * 16 + lrow];
    const int rowg0 = row0 + wrow + rq;
#pragma unroll
    for (int rr = 0; rr < 4; ++rr) {
      const float m = (float)mask[rowg0 + rr];
      float kf[4];
#pragma unroll
      for (int j = 0; j < 4; ++j) kf[j] = (acc[j][rr] + bkc[j]) * m;
      float mx = fmaxf(fmaxf(kf[0], kf[1]), fmaxf(kf[2], kf[3]));
#pragma unroll
      for (int off = 8; off >= 1; off >>= 1) mx = fmaxf(mx, __shfl_xor(mx, off));
      float s = 0.0f;
#pragma unroll
      for (int j = 0; j < 4; ++j) { kf[j] = expf(kf[j] - mx); s += kf[j]; }
#pragma unroll
      for (int off = 8; off >= 1; off >>= 1) s += __shfl_xor(s, off);
      const float inv = 1.0f / s;
#pragma unroll
      for (int j = 0; j < 4; ++j)
        acc[j][rr] = kf[j] * inv * bf2f(Vs[wrow + rq + rr][j * 16 + lrow]);
    }
#pragma unroll
    for (int j = 0; j < 4; ++j) {
      const int d = j * 16 + lrow;
      short4 o;
      o.x = f2bf(acc[j][0]); o.y = f2bf(acc[j][1]);
      o.z = f2bf(acc[j][2]); o.w = f2bf(acc[j][3]);
      *(short4*)&kvS[d][wrow + rq] = o;
    }
  }
  __syncthreads();
  // Mt contraction: waves 0-3 cover e in [wv*16, wv*16+16), K = 128 local l.
  if (wv < 4) {
    const int bb = row0 >> 11;
    const int tb = row0 & 2047;
    const short* tkb = tkT + (size_t)(wv * 16 + lrow) * 2048 + tb;
    const int kg = (lane >> 4) * 8;
    f32x4 macc[4] = {};
#pragma unroll
    for (int kc = 0; kc < 4; ++kc) {
      const bfx8 af = *(const bfx8*)(tkb + kc * 32 + kg);
#pragma unroll
      for (int j = 0; j < 4; ++j) {
        const bfx8 bf_ = *(const bfx8*)&kvS[j * 16 + lrow][kc * 32 + kg];
        macc[j] = __builtin_amdgcn_mfma_f32_16x16x32_bf16(af, bf_, macc[j], 0, 0, 0);
      }
    }
    float* Mb = Mt + (size_t)(bb * 16 + h) * 4096;
#pragma unroll
    for (int j = 0; j < 4; ++j) {
      const int d = j * 16 + lrow;
#pragma unroll
      for (int rr = 0; rr < 4; ++rr) {
        const int e = wv * 16 + rq + rr;
        atomicAdd(&Mb[(size_t)e * 64 + d], macc[j][rr]);
      }
    }
  }
}

// ---------------- fold fused into hgemm (proven r1-r3) ---------------------
// H[b][o][kap] = sum_k Wo[o][k] Mf[b][kap][k]; fold applied in-register:
//   Mf[b][a][h*64+d]    = p*Mt[b,h][a][d] + q*Mt[b,h][32+a][d]
//   Mf[b][32+a][h*64+d] = q*Mt[b,h][a][d] - p*Mt[b,h][32+a][d]
// 256 blocks: (h2:8 head pairs) x (ot:16 o-tiles) x (b:2), K=128 per block.
__global__ __launch_bounds__(256) void foldhgemm_kernel(
    const short* __restrict__ Wob, const float* __restrict__ Mt,
    const float* __restrict__ angles, const float* __restrict__ delta,
    float* __restrict__ H) {
  const int bid = blockIdx.x;
  const int t = threadIdx.x;
  const int lane = t & 63;
  const int w = t >> 6;
  const int lrow = lane & 15;
  const int kg = (lane >> 4) * 8;
  const int h2 = bid & 7;
  const int ot = (bid >> 3) & 15;
  const int b = bid >> 7;
  const int orow = ot * 64 + w * 16 + lrow;
  float p[2][2], q[2][2];
#pragma unroll
  for (int hh = 0; hh < 2; ++hh) {
    const float dl = delta[h2 * 2 + hh];
#pragma unroll
    for (int aa = 0; aa < 2; ++aa) {
      float s, c;
      sincosf(dl * angles[aa * 16 + lrow], &s, &c);
      p[hh][aa] = c + s;
      q[hh][aa] = c - s;
    }
  }
  f32x4 acc[4] = {};
#pragma unroll
  for (int ks = 0; ks < 4; ++ks) {
    const int hh = ks >> 1;
    const int h = h2 * 2 + hh;
    const int d0 = (ks & 1) * 32 + kg;
    const float* Mthb = Mt + (size_t)(b * 16 + h) * 4096;
    const bfx8 af = *(const bfx8*)(Wob + (size_t)orow * 1024 + h * 64 + d0);
    float m0a[8], m1a[8], m0b[8], m1b[8];
    *(float4*)&m0a[0] = *(const float4*)(Mthb + lrow * 64 + d0);
    *(float4*)&m0a[4] = *(const float4*)(Mthb + lrow * 64 + d0 + 4);
    *(float4*)&m1a[0] = *(const float4*)(Mthb + (32 + lrow) * 64 + d0);
    *(float4*)&m1a[4] = *(const float4*)(Mthb + (32 + lrow) * 64 + d0 + 4);
    *(float4*)&m0b[0] = *(const float4*)(Mthb + (16 + lrow) * 64 + d0);
    *(float4*)&m0b[4] = *(const float4*)(Mthb + (16 + lrow) * 64 + d0 + 4);
    *(float4*)&m1b[0] = *(const float4*)(Mthb + (48 + lrow) * 64 + d0);
    *(float4*)&m1b[4] = *(const float4*)(Mthb + (48 + lrow) * 64 + d0 + 4);
    bfx8 bf0, bf1, bf2, bf3;
#pragma unroll
    for (int e = 0; e < 8; ++e) {
      bf0[e] = f2bf(p[hh][0] * m0a[e] + q[hh][0] * m1a[e]);
      bf1[e] = f2bf(p[hh][1] * m0b[e] + q[hh][1] * m1b[e]);
      bf2[e] = f2bf(q[hh][0] * m0a[e] - p[hh][0] * m1a[e]);
      bf3[e] = f2bf(q[hh][1] * m0b[e] - p[hh][1] * m1b[e]);
    }
    acc[0] = __builtin_amdgcn_mfma_f32_16x16x32_bf16(af, bf0, acc[0], 0, 0, 0);
    acc[1] = __builtin_amdgcn_mfma_f32_16x16x32_bf16(af, bf1, acc[1], 0, 0, 0);
    acc[2] = __builtin_amdgcn_mfma_f32_16x16x32_bf16(af, bf2, acc[2], 0, 0, 0);
    acc[3] = __builtin_amdgcn_mfma_f32_16x16x32_bf16(af, bf3, acc[3], 0, 0, 0);
  }
  float* Hb = H + (size_t)b * 65536;
  const int rq = (lane >> 4) * 4;
#pragma unroll
  for (int j = 0; j < 4; ++j) {
    const int kap = j * 16 + lrow;
#pragma unroll
    for (int rr = 0; rr < 4; ++rr) {
      const int o = ot * 64 + w * 16 + rq + rr;
      atomicAdd(&Hb[(size_t)o * 64 + kap], acc[j][rr]);
    }
  }
}

// ---------------- out[b][t][o] = sum_kap Cb[t][kap]*H[b][o][kap] + bo[o] ----
__global__ __launch_bounds__(256) void ofinal_kernel(
    const short* __restrict__ Cb, const float* __restrict__ H,
    const float* __restrict__ bo, float* __restrict__ out) {
  const int col0 = blockIdx.x * 128;
  const int row0 = blockIdx.y * 128;
  const int b = blockIdx.z;
  float* C = out + (size_t)b * 2097152;
  const float* Hb = H + (size_t)b * 65536;
  const int t = threadIdx.x;
  const int lane = t & 63;
  const int wv = t >> 6;
  const int wm = (wv & 1) * 64, wn = (wv >> 1) * 64;
  const int lrow = lane & 15;
  const int kg = (lane >> 4) * 8;
  f32x4 acc[4][4] = {};
#pragma unroll
  for (int k0 = 0; k0 < 64; k0 += 32) {
    bfx8 af[4], bf_[4];
#pragma unroll
    for (int i = 0; i < 4; ++i)
      af[i] = *(const bfx8*)(Cb + (size_t)(row0 + wm + i * 16 + lrow) * 64 + k0 + kg);
#pragma unroll
    for (int j = 0; j < 4; ++j) {
      const float* hp = Hb + (size_t)(col0 + wn + j * 16 + lrow) * 64 + k0 + kg;
      const float4 h0 = *(const float4*)hp;
      const float4 h1 = *(const float4*)(hp + 4);
      bfx8 bb;
      bb[0] = f2bf(h0.x); bb[1] = f2bf(h0.y); bb[2] = f2bf(h0.z); bb[3] = f2bf(h0.w);
      bb[4] = f2bf(h1.x); bb[5] = f2bf(h1.y); bb[6] = f2bf(h1.z); bb[7] = f2bf(h1.w);
      bf_[j] = bb;
    }
#pragma unroll
    for (int i = 0; i < 4; ++i)
#pragma unroll
      for (int j = 0; j < 4; ++j)
        acc[i][j] = __builtin_amdgcn_mfma_f32_16x16x32_bf16(af[i], bf_[j], acc[i][j], 0, 0, 0);
  }
  const int rq = (lane >> 4) * 4;
#pragma unroll
  for (int j = 0; j < 4; ++j) {
    const int c = col0 + wn + j * 16 + lrow;
    const float bb = bo[c];
#pragma unroll
    for (int i = 0; i < 4; ++i) {
      const int r = row0 + wm + i * 16 + rq;
#pragma unroll
      for (int rr = 0; rr < 4; ++rr)
        C[(size_t)(r + rr) * 1024 + c] = acc[i][j][rr] + bb;
    }
  }
}

extern "C" void kernel_launch(void* const* d_in, const int* in_sizes, int n_in,
                              void* d_out, int out_size, void* d_ws, size_t ws_size,
                              hipStream_t stream) {
  (void)in_sizes; (void)n_in; (void)out_size; (void)ws_size;
  const float* states = (const float*)d_in[0];
  const int* mask = (const int*)d_in[1];
  const float* ln_w = (const float*)d_in[2];
  const float* angles = (const float*)d_in[3];
  const float* delta = (const float*)d_in[4];
  // d_in[5]=Wq, d_in[6]=q_bias provably unused (softmax row-sums are 1).
  const float* Wk = (const float*)d_in[7];
  const float* bk = (const float*)d_in[8];
  const float* Wv = (const float*)d_in[9];
  const float* bv = (const float*)d_in[10];
  const float* Wo = (const float*)d_in[11];
  const float* bo = (const float*)d_in[12];
  float* out = (float*)d_out;

  char* W = (char*)d_ws;
  short* xb  = (short*)(W);                        // 8 MB   [4096][1024]
  short* Wkb = (short*)(W + (8u << 20));           // 2 MB
  short* Wvb = (short*)(W + (10u << 20));          // 2 MB
  short* Wob = (short*)(W + (12u << 20));          // 2 MB
  short* Cb  = (short*)(W + (14u << 20));          // 256 KB [2048][64]
  short* tkT = (short*)(W + (14u << 20) + (256u << 10));  // 256 KB [64][2048]
  float* Mt  = (float*)(W + (15u << 20));          // 512 KB [32][64][64]
  float* H   = (float*)(W + (15u << 20) + (512u << 10));  // 512 KB [2][1024][64]

  prep_kernel<<<7712, 256, 0, stream>>>(Wk, Wv, Wo, angles, states, ln_w,
                                        Wkb, Wvb, Wob, xb, Cb, tkT, Mt);
  kvgemm_kernel<<<dim3(32, 16), 1024, 0, stream>>>(xb, Wkb, Wvb, bk, bv, mask,
                                                   tkT, Mt);
  foldhgemm_kernel<<<256, 256, 0, stream>>>(Wob, Mt, angles, delta, H);
  ofinal_kernel<<<dim3(8, 16, 2), 256, 0, stream>>>(Cb, H, bo, out);
}

// Round 11
// 142.285 us; speedup vs baseline: 1.3011x; 1.0103x over previous
//
#include <hip/hip_runtime.h>
#include <math.h>

#define T_ 2048
#define H_ 16

typedef __attribute__((ext_vector_type(8))) short bfx8;   // 8 bf16 = 4 VGPRs
typedef __attribute__((ext_vector_type(4))) float f32x4;  // MFMA accumulator

__device__ __forceinline__ short f2bf(float f) {
  union { float f; unsigned u; } x; x.f = f;
  unsigned r = (x.u + 0x7FFFu + ((x.u >> 16) & 1u)) >> 16;  // RNE
  return (short)r;
}
__device__ __forceinline__ float bf2f(short s) {
  union { unsigned u; float f; } x;
  x.u = ((unsigned)(unsigned short)s) << 16;
  return x.f;
}

#define GLD_LDS(g, l) \
  __builtin_amdgcn_global_load_lds( \
      (const __attribute__((address_space(1))) void*)(g), \
      (__attribute__((address_space(3))) void*)(l), 16, 0, 0)

// ---------------- prep: weight cvt + RMSNorm + Cb basis + tk table + Mt/H zero
__global__ __launch_bounds__(256) void prep_kernel(
    const float* __restrict__ Wk, const float* __restrict__ Wv,
    const float* __restrict__ Wo, const float* __restrict__ angles,
    const float* __restrict__ states, const float* __restrict__ ln_w,
    short* __restrict__ Wkb, short* __restrict__ Wvb, short* __restrict__ Wob,
    short* __restrict__ xb, short* __restrict__ Cb, short* __restrict__ tkT,
    float* __restrict__ MtH) {
  const int blk = blockIdx.x;
  if (blk < 3072) {
    const int i = blk * 256 + threadIdx.x;
    const int which = i >> 18;
    const int idx = i & 262143;
    const float* s = (which == 0) ? Wk : (which == 1) ? Wv : Wo;
    short* d = (which == 0) ? Wkb : (which == 1) ? Wvb : Wob;
    const float4 v = ((const float4*)s)[idx];
    short4 r;
    r.x = f2bf(v.x); r.y = f2bf(v.y); r.z = f2bf(v.z); r.w = f2bf(v.w);
    ((short4*)d)[idx] = r;
  } else if (blk < 7168) {
    const int row = blk - 3072;
    const int tid = threadIdx.x;
    const float4 v = ((const float4*)(states + (size_t)row * 1024))[tid];
    float ss = v.x * v.x + v.y * v.y + v.z * v.z + v.w * v.w;
#pragma unroll
    for (int off = 32; off >= 1; off >>= 1) ss += __shfl_xor(ss, off);
    __shared__ float red[4];
    if ((tid & 63) == 0) red[tid >> 6] = ss;
    __syncthreads();
    const float tot = red[0] + red[1] + red[2] + red[3];
    const float scale = rsqrtf(tot * (1.0f / 1024.0f) + 1.1920928955078125e-07f);
    const float4 w = ((const float4*)ln_w)[tid];
    short4 o;
    o.x = f2bf(v.x * scale * w.x);
    o.y = f2bf(v.y * scale * w.y);
    o.z = f2bf(v.z * scale * w.z);
    o.w = f2bf(v.w * scale * w.w);
    ((short4*)(xb + (size_t)row * 1024))[tid] = o;
  } else if (blk < 7424) {
    const int gid = (blk - 7168) * 256 + threadIdx.x;  // 64K: (t,j)
    const int j = gid & 31;
    const int t = gid >> 5;
    float s, c;
    sincosf((float)t * angles[j], &s, &c);
    Cb[(size_t)t * 64 + j] = f2bf(0.125f * c);
    Cb[(size_t)t * 64 + 32 + j] = f2bf(0.125f * s);
  } else if (blk < 7456) {
    const int gid = (blk - 7424) * 256 + threadIdx.x;  // 8K: (j, l-chunk)
    const int tc = gid & 255;
    const int j = gid >> 8;
    const float th = angles[j];
    short lo[8], hi[8];
#pragma unroll
    for (int r = 0; r < 8; ++r) {
      float s, c;
      sincosf((float)(tc * 8 + r) * th, &s, &c);
      lo[r] = f2bf((c + s) * 0.125f);
      hi[r] = f2bf((c - s) * 0.125f);
    }
    short* base = tkT + (size_t)j * 2048 + tc * 8;
    *(short4*)(base) = *(short4*)&lo[0];
    *(short4*)(base + 4) = *(short4*)&lo[4];
    short* base2 = tkT + (size_t)(32 + j) * 2048 + tc * 8;
    *(short4*)(base2) = *(short4*)&hi[0];
    *(short4*)(base2 + 4) = *(short4*)&hi[4];
  } else {  // zero Mt (512 KB) + H (512 KB): 65536 float4s
    const int gid = (blk - 7456) * 256 + threadIdx.x;
    ((float4*)MtH)[gid] = make_float4(0.f, 0.f, 0.f, 0.f);
  }
}

// ------- fused K+V GEMM + masked softmax + kv + Mt accumulation -------------
// r11: r10 (1024 thr, 16 waves, 32 waves/CU) + compile-time double-buffer.
// r2's dbuf regression had two confounds, both removed here: (a) occupancy
// loss (3->2 blocks at 256thr) — at 1024thr, 64KB x 2 blocks still hits the
// 32-wave/CU hardware cap exactly; (b) runtime smem[cur] base defeating
// ds_read offset folding (VGPR 80->132) — here the K-loop is unrolled x2 with
// LITERAL buffer indices (STAGE(0/1)/COMPUTE(0/1)), all LDS addresses static.
// Effect: one barrier per K-step (32 -> 17) and each step's 2 GLD_LDS issue
// before the other buffer's 8 MFMA, hiding ~400cy load latency under compute.
// Ladder: 256thr 43us -> 512thr ~39 -> 1024thr ~36 -> this.
__global__ __launch_bounds__(1024, 8) void kvgemm_kernel(
    const short* __restrict__ xb, const short* __restrict__ Wkb,
    const short* __restrict__ Wvb, const float* __restrict__ bk,
    const float* __restrict__ bv, const int* __restrict__ mask,
    const short* __restrict__ tkT, float* __restrict__ Mt) {
  // buf B at smem + B*16384 (shorts): As[128][64] | Bk[64][64] | Bv[64][64]
  // post-loop overlay: Vs[128][64] @0 | kvS[64][132] @8192
  __shared__ short smem[32768];  // 64 KB
  short(*Vs)[64] = (short(*)[64])smem;
  short(*kvS)[132] = (short(*)[132])(smem + 8192);

  const int row0 = blockIdx.x * 128;  // XCD = x%8
  const int h = blockIdx.y;
  const int t = threadIdx.x;          // 0..1023
  const int lane = t & 63;
  const int wv = t >> 6;              // 0..15
  const bool isV = wv >= 8;
  const int wrow = (wv & 7) * 16;     // 16-row band per wave
  const int lrow = lane & 15;

  // staging: thread t owns physical slot t&7 of row t>>3 (0..127); fetches
  // k-slot (t&7)^(row&7). One A issue; waves 0-7 stage Bk, 8-15 Bv.
  const int srow8 = t >> 3;  // 0..127
  const int kslotS = (t & 7) ^ (srow8 & 7);
  const short* gaS = xb + (size_t)(row0 + srow8) * 1024 + kslotS * 8;
  const short* gbS = isV ? Wvb + (size_t)(h * 64 + srow8 - 64) * 1024 + kslotS * 8
                         : Wkb + (size_t)(h * 64 + srow8) * 1024 + kslotS * 8;
  short* laS = smem + srow8 * 64 + (t & 7) * 8;  // As row slot (buf 0)
  short* lbS = isV ? smem + 12288 + (srow8 - 64) * 64 + (t & 7) * 8
                   : smem + 8192 + srow8 * 64 + (t & 7) * 8;
  const int bOff = isV ? 12288 : 8192;  // B-matrix base within a buffer

#define STAGE(B, K)                        \
  do {                                     \
    GLD_LDS(gaS + (K), laS + (B) * 16384); \
    GLD_LDS(gbS + (K), lbS + (B) * 16384); \
  } while (0)

#define COMPUTE(B)                                                            \
  do {                                                                        \
    const short(*As_)[64] = (const short(*)[64])(smem + (B) * 16384);         \
    const short(*Bs_)[64] = (const short(*)[64])(smem + (B) * 16384 + bOff);  \
    _Pragma("unroll")                                                         \
    for (int kk = 0; kk < 2; ++kk) {                                          \
      const int pcol = ((kk * 4 + (lane >> 4)) ^ (lrow & 7)) * 8;             \
      const bfx8 af = *(const bfx8*)&As_[wrow + lrow][pcol];                  \
      bfx8 bf_[4];                                                            \
      _Pragma("unroll")                                                       \
      for (int j = 0; j < 4; ++j)                                             \
        bf_[j] = *(const bfx8*)&Bs_[j * 16 + lrow][pcol];                     \
      _Pragma("unroll")                                                       \
      for (int j = 0; j < 4; ++j)                                             \
        acc[j] = __builtin_amdgcn_mfma_f32_16x16x32_bf16(af, bf_[j], acc[j],  \
                                                         0, 0, 0);            \
    }                                                                         \
  } while (0)

  f32x4 acc[4] = {};
  STAGE(0, 0);
  __syncthreads();  // drains prologue stage
  for (int k0 = 0; k0 < 1024; k0 += 128) {
    STAGE(1, k0 + 64);        // prefetch odd step into buf1
    COMPUTE(0);               // MFMA from buf0 meanwhile
    __syncthreads();          // buf1 ready; all done reading buf0
    if (k0 + 128 < 1024) STAGE(0, k0 + 128);  // prefetch next even step
    COMPUTE(1);
    __syncthreads();          // buf0 ready; all done reading buf1
  }
#undef STAGE
#undef COMPUTE

  const int rq = (lane >> 4) * 4;
  if (isV) {  // park V+bias in Vs (aliases buf0 As; post-loop, barrier-safe)
#pragma unroll
    for (int j = 0; j < 4; ++j) {
      const float bb = bv[h * 64 + j * 16 + lrow];
#pragma unroll
      for (int rr = 0; rr < 4; ++rr)
        Vs[wrow + rq + rr][j * 16 + lrow] = f2bf(acc[j][rr] + bb);
    }
  }
  __syncthreads();
  if (!isV) {  // masked softmax over head dim, kv = softmax * V -> kvS[d][l]
    float bkc[4];
#pragma unroll
    for (int j = 0; j < 4; ++j) bkc[j] = bk[h * 64 + j * 16 + lrow];
    const int rowg0 = row0 + wrow + rq;
#pragma unroll
    for (int rr = 0; rr < 4; ++rr) {
      const float m = (float)mask[rowg0 + rr];
      float kf[4];
#pragma unroll
      for (int j = 0; j < 4; ++j) kf[j] = (acc[j][rr] + bkc[j]) * m;
      float mx = fmaxf(fmaxf(kf[0], kf[1]), fmaxf(kf[2], kf[3]));
#pragma unroll
      for (int off = 8; off >= 1; off >>= 1) mx = fmaxf(mx, __shfl_xor(mx, off));
      float s = 0.0f;
#pragma unroll
      for (int j = 0; j < 4; ++j) { kf[j] = expf(kf[j] - mx); s += kf[j]; }
#pragma unroll
      for (int off = 8; off >= 1; off >>= 1) s += __shfl_xor(s, off);
      const float inv = 1.0f / s;
#pragma unroll
      for (int j = 0; j < 4; ++j)
        acc[j][rr] = kf[j] * inv * bf2f(Vs[wrow + rq + rr][j * 16 + lrow]);
    }
#pragma unroll
    for (int j = 0; j < 4; ++j) {
      const int d = j * 16 + lrow;
      short4 o;
      o.x = f2bf(acc[j][0]); o.y = f2bf(acc[j][1]);
      o.z = f2bf(acc[j][2]); o.w = f2bf(acc[j][3]);
      *(short4*)&kvS[d][wrow + rq] = o;
    }
  }
  __syncthreads();
  // Mt contraction: waves 0-3 cover e in [wv*16, wv*16+16), K = 128 local l.
  if (wv < 4) {
    const int bb = row0 >> 11;
    const int tb = row0 & 2047;
    const short* tkb = tkT + (size_t)(wv * 16 + lrow) * 2048 + tb;
    const int kg = (lane >> 4) * 8;
    f32x4 macc[4] = {};
#pragma unroll
    for (int kc = 0; kc < 4; ++kc) {
      const bfx8 af = *(const bfx8*)(tkb + kc * 32 + kg);
#pragma unroll
      for (int j = 0; j < 4; ++j) {
        const bfx8 bf_ = *(const bfx8*)&kvS[j * 16 + lrow][kc * 32 + kg];
        macc[j] = __builtin_amdgcn_mfma_f32_16x16x32_bf16(af, bf_, macc[j], 0, 0, 0);
      }
    }
    float* Mb = Mt + (size_t)(bb * 16 + h) * 4096;
#pragma unroll
    for (int j = 0; j < 4; ++j) {
      const int d = j * 16 + lrow;
#pragma unroll
      for (int rr = 0; rr < 4; ++rr) {
        const int e = wv * 16 + rq + rr;
        atomicAdd(&Mb[(size_t)e * 64 + d], macc[j][rr]);
      }
    }
  }
}

// ---------------- fold fused into hgemm (proven r1-r3) ---------------------
// H[b][o][kap] = sum_k Wo[o][k] Mf[b][kap][k]; fold applied in-register:
//   Mf[b][a][h*64+d]    = p*Mt[b,h][a][d] + q*Mt[b,h][32+a][d]
//   Mf[b][32+a][h*64+d] = q*Mt[b,h][a][d] - p*Mt[b,h][32+a][d]
// 256 blocks: (h2:8 head pairs) x (ot:16 o-tiles) x (b:2), K=128 per block.
__global__ __launch_bounds__(256) void foldhgemm_kernel(
    const short* __restrict__ Wob, const float* __restrict__ Mt,
    const float* __restrict__ angles, const float* __restrict__ delta,
    float* __restrict__ H) {
  const int bid = blockIdx.x;
  const int t = threadIdx.x;
  const int lane = t & 63;
  const int w = t >> 6;
  const int lrow = lane & 15;
  const int kg = (lane >> 4) * 8;
  const int h2 = bid & 7;
  const int ot = (bid >> 3) & 15;
  const int b = bid >> 7;
  const int orow = ot * 64 + w * 16 + lrow;
  float p[2][2], q[2][2];
#pragma unroll
  for (int hh = 0; hh < 2; ++hh) {
    const float dl = delta[h2 * 2 + hh];
#pragma unroll
    for (int aa = 0; aa < 2; ++aa) {
      float s, c;
      sincosf(dl * angles[aa * 16 + lrow], &s, &c);
      p[hh][aa] = c + s;
      q[hh][aa] = c - s;
    }
  }
  f32x4 acc[4] = {};
#pragma unroll
  for (int ks = 0; ks < 4; ++ks) {
    const int hh = ks >> 1;
    const int h = h2 * 2 + hh;
    const int d0 = (ks & 1) * 32 + kg;
    const float* Mthb = Mt + (size_t)(b * 16 + h) * 4096;
    const bfx8 af = *(const bfx8*)(Wob + (size_t)orow * 1024 + h * 64 + d0);
    float m0a[8], m1a[8], m0b[8], m1b[8];
    *(float4*)&m0a[0] = *(const float4*)(Mthb + lrow * 64 + d0);
    *(float4*)&m0a[4] = *(const float4*)(Mthb + lrow * 64 + d0 + 4);
    *(float4*)&m1a[0] = *(const float4*)(Mthb + (32 + lrow) * 64 + d0);
    *(float4*)&m1a[4] = *(const float4*)(Mthb + (32 + lrow) * 64 + d0 + 4);
    *(float4*)&m0b[0] = *(const float4*)(Mthb + (16 + lrow) * 64 + d0);
    *(float4*)&m0b[4] = *(const float4*)(Mthb + (16 + lrow) * 64 + d0 + 4);
    *(float4*)&m1b[0] = *(const float4*)(Mthb + (48 + lrow) * 64 + d0);
    *(float4*)&m1b[4] = *(const float4*)(Mthb + (48 + lrow) * 64 + d0 + 4);
    bfx8 bf0, bf1, bf2, bf3;
#pragma unroll
    for (int e = 0; e < 8; ++e) {
      bf0[e] = f2bf(p[hh][0] * m0a[e] + q[hh][0] * m1a[e]);
      bf1[e] = f2bf(p[hh][1] * m0b[e] + q[hh][1] * m1b[e]);
      bf2[e] = f2bf(q[hh][0] * m0a[e] - p[hh][0] * m1a[e]);
      bf3[e] = f2bf(q[hh][1] * m0b[e] - p[hh][1] * m1b[e]);
    }
    acc[0] = __builtin_amdgcn_mfma_f32_16x16x32_bf16(af, bf0, acc[0], 0, 0, 0);
    acc[1] = __builtin_amdgcn_mfma_f32_16x16x32_bf16(af, bf1, acc[1], 0, 0, 0);
    acc[2] = __builtin_amdgcn_mfma_f32_16x16x32_bf16(af, bf2, acc[2], 0, 0, 0);
    acc[3] = __builtin_amdgcn_mfma_f32_16x16x32_bf16(af, bf3, acc[3], 0, 0, 0);
  }
  float* Hb = H + (size_t)b * 65536;
  const int rq = (lane >> 4) * 4;
#pragma unroll
  for (int j = 0; j < 4; ++j) {
    const int kap = j * 16 + lrow;
#pragma unroll
    for (int rr = 0; rr < 4; ++rr) {
      const int o = ot * 64 + w * 16 + rq + rr;
      atomicAdd(&Hb[(size_t)o * 64 + kap], acc[j][rr]);
    }
  }
}

// ---------------- out[b][t][o] = sum_kap Cb[t][kap]*H[b][o][kap] + bo[o] ----
__global__ __launch_bounds__(256) void ofinal_kernel(
    const short* __restrict__ Cb, const float* __restrict__ H,
    const float* __restrict__ bo, float* __restrict__ out) {
  const int col0 = blockIdx.x * 128;
  const int row0 = blockIdx.y * 128;
  const int b = blockIdx.z;
  float* C = out + (size_t)b * 2097152;
  const float* Hb = H + (size_t)b * 65536;
  const int t = threadIdx.x;
  const int lane = t & 63;
  const int wv = t >> 6;
  const int wm = (wv & 1) * 64, wn = (wv >> 1) * 64;
  const int lrow = lane & 15;
  const int kg = (lane >> 4) * 8;
  f32x4 acc[4][4] = {};
#pragma unroll
  for (int k0 = 0; k0 < 64; k0 += 32) {
    bfx8 af[4], bf_[4];
#pragma unroll
    for (int i = 0; i < 4; ++i)
      af[i] = *(const bfx8*)(Cb + (size_t)(row0 + wm + i * 16 + lrow) * 64 + k0 + kg);
#pragma unroll
    for (int j = 0; j < 4; ++j) {
      const float* hp = Hb + (size_t)(col0 + wn + j * 16 + lrow) * 64 + k0 + kg;
      const float4 h0 = *(const float4*)hp;
      const float4 h1 = *(const float4*)(hp + 4);
      bfx8 bb;
      bb[0] = f2bf(h0.x); bb[1] = f2bf(h0.y); bb[2] = f2bf(h0.z); bb[3] = f2bf(h0.w);
      bb[4] = f2bf(h1.x); bb[5] = f2bf(h1.y); bb[6] = f2bf(h1.z); bb[7] = f2bf(h1.w);
      bf_[j] = bb;
    }
#pragma unroll
    for (int i = 0; i < 4; ++i)
#pragma unroll
      for (int j = 0; j < 4; ++j)
        acc[i][j] = __builtin_amdgcn_mfma_f32_16x16x32_bf16(af[i], bf_[j], acc[i][j], 0, 0, 0);
  }
  const int rq = (lane >> 4) * 4;
#pragma unroll
  for (int j = 0; j < 4; ++j) {
    const int c = col0 + wn + j * 16 + lrow;
    const float bb = bo[c];
#pragma unroll
    for (int i = 0; i < 4; ++i) {
      const int r = row0 + wm + i * 16 + rq;
#pragma unroll
      for (int rr = 0; rr < 4; ++rr)
        C[(size_t)(r + rr) * 1024 + c] = acc[i][j][rr] + bb;
    }
  }
}

extern "C" void kernel_launch(void* const* d_in, const int* in_sizes, int n_in,
                              void* d_out, int out_size, void* d_ws, size_t ws_size,
                              hipStream_t stream) {
  (void)in_sizes; (void)n_in; (void)out_size; (void)ws_size;
  const float* states = (const float*)d_in[0];
  const int* mask = (const int*)d_in[1];
  const float* ln_w = (const float*)d_in[2];
  const float* angles = (const float*)d_in[3];
  const float* delta = (const float*)d_in[4];
  // d_in[5]=Wq, d_in[6]=q_bias provably unused (softmax row-sums are 1).
  const float* Wk = (const float*)d_in[7];
  const float* bk = (const float*)d_in[8];
  const float* Wv = (const float*)d_in[9];
  const float* bv = (const float*)d_in[10];
  const float* Wo = (const float*)d_in[11];
  const float* bo = (const float*)d_in[12];
  float* out = (float*)d_out;

  char* W = (char*)d_ws;
  short* xb  = (short*)(W);                        // 8 MB   [4096][1024]
  short* Wkb = (short*)(W + (8u << 20));           // 2 MB
  short* Wvb = (short*)(W + (10u << 20));          // 2 MB
  short* Wob = (short*)(W + (12u << 20));          // 2 MB
  short* Cb  = (short*)(W + (14u << 20));          // 256 KB [2048][64]
  short* tkT = (short*)(W + (14u << 20) + (256u << 10));  // 256 KB [64][2048]
  float* Mt  = (float*)(W + (15u << 20));          // 512 KB [32][64][64]
  float* H   = (float*)(W + (15u << 20) + (512u << 10));  // 512 KB [2][1024][64]

  prep_kernel<<<7712, 256, 0, stream>>>(Wk, Wv, Wo, angles, states, ln_w,
                                        Wkb, Wvb, Wob, xb, Cb, tkT, Mt);
  kvgemm_kernel<<<dim3(32, 16), 1024, 0, stream>>>(xb, Wkb, Wvb, bk, bv, mask,
                                                   tkT, Mt);
  foldhgemm_kernel<<<256, 256, 0, stream>>>(Wob, Mt, angles, delta, H);
  ofinal_kernel<<<dim3(8, 16, 2), 256, 0, stream>>>(Cb, H, bo, out);
}